// Round 4
// baseline (593.735 us; speedup 1.0000x reference)
//
#include <hip/hip_runtime.h>
#include <stdint.h>

typedef unsigned short u16;
typedef float f32x4 __attribute__((ext_vector_type(4)));
typedef short s16x8 __attribute__((ext_vector_type(8)));

#define DEV __device__ __forceinline__

DEV float b2f(u16 u){ union{unsigned i; float f;} v; v.i = ((unsigned)u)<<16; return v.f; }
DEV u16 f2b(float f){ union{float f; unsigned i;} v; v.f=f; unsigned u=v.i;
                      return (u16)((u + 0x7FFFu + ((u>>16)&1u))>>16); }
DEV s16x8 ld8(const u16* p){ return *(const s16x8*)p; }

// MFMA with embedded pre-nop: covers VALU-write -> MFMA-Src read hazard (<=2 waits)
// regardless of how the scheduler places surrounding VALU ops.
DEV void mfma_bf16(f32x4& d, s16x8 a, s16x8 b){
  asm volatile("s_nop 1\n\tv_mfma_f32_16x16x32_bf16 %0, %1, %2, %0"
               : "+v"(d) : "v"(a), "v"(b));
}
// Operand-TIED post-fence: accumulators are read+written by this asm, so the
// compiler cannot sink later reads above it nor hoist it above the MFMAs.
// 16 nop-cycles > 11 required for 16x16 XDL D -> VALU RAW.
DEV void accfence(f32x4& a){ asm volatile("s_nop 7\n\ts_nop 7" : "+v"(a)); }
DEV void accfence4(f32x4& a, f32x4& b, f32x4& c, f32x4& d){
  asm volatile("s_nop 7\n\ts_nop 7" : "+v"(a), "+v"(b), "+v"(c), "+v"(d));
}

// ---------------- dtype detection: f32 misread as bf16 has wild exponents ---
__global__ __launch_bounds__(64) void detect_kernel(const u16* __restrict__ x, int* flag){
  int lane = threadIdx.x;
  int cnt = 0;
  for (int i=0;i<32;i++){
    u16 v = x[lane*32+i];
    int e = (v >> 7) & 0xFF;
    if (e >= 0xE0) cnt++;           // |val| >= 2^97: impossible for N(0,1) bf16 data
  }
  for (int off=1; off<64; off<<=1) cnt += __shfl_xor(cnt, off, 64);
  if (lane==0) *flag = (cnt >= 16) ? 1 : 0;   // 1 = device buffers are f32
}

// ---------------- canonicalize all input tensors to contiguous bf16 ---------
struct NormArgs { const void* src[23]; int cumblk[24]; };

__global__ __launch_bounds__(64) void norm_kernel(NormArgs a, const int* __restrict__ flag,
                                                  u16* __restrict__ canon){
  int b = blockIdx.x, lane = threadIdx.x;
  int t = 0;
  while (t < 22 && b >= a.cumblk[t+1]) t++;
  int off = (b - a.cumblk[t])*512 + lane*8;
  size_t g = (size_t)b*512 + lane*8;
  if (*flag){
    const float* s = (const float*)a.src[t] + off;
    s16x8 o;
#pragma unroll
    for (int j=0;j<8;j++) o[j] = (short)f2b(s[j]);
    *(s16x8*)(canon+g) = o;
  } else {
    *(s16x8*)(canon+g) = *(const s16x8*)((const u16*)a.src[t] + off);
  }
}

// ---------------- generic MFMA GEMM: C = A(MxK) @ BT(NxK)^T + bias ----------
// out_f/out_bf: unconditional ws outputs. dev_bf/dev_f: flag-selected d_out region.
__global__ __launch_bounds__(256) void gemm_kernel(
    const u16* __restrict__ A, const u16* __restrict__ BT, const u16* __restrict__ bias,
    int M, int N, int K,
    const u16* __restrict__ resid_bf, const float* __restrict__ resid_f,
    u16* __restrict__ out_bf, float* __restrict__ out_f,
    const int* __restrict__ flagp, u16* __restrict__ dev_bf, float* __restrict__ dev_f,
    int relu)
{
  int tid = threadIdx.x, lane = tid & 63, wid = tid >> 6;
  int wm = wid >> 1, wn = wid & 1;
  int lr = lane & 15, lk = lane >> 4;
  int rowBase = blockIdx.y*64 + wm*32;
  int colBase = blockIdx.x*64 + wn*32;
  int ar0 = min(rowBase + lr, M-1);
  int ar1 = min(rowBase + 16 + lr, M-1);
  int bc0 = colBase + lr, bc1 = colBase + 16 + lr;   // N is a multiple of 64
  const u16* pa0 = A  + (size_t)ar0*K + lk*8;
  const u16* pa1 = A  + (size_t)ar1*K + lk*8;
  const u16* pb0 = BT + (size_t)bc0*K + lk*8;
  const u16* pb1 = BT + (size_t)bc1*K + lk*8;
  f32x4 acc00={0,0,0,0}, acc01={0,0,0,0}, acc10={0,0,0,0}, acc11={0,0,0,0};
#pragma unroll 4
  for (int k0 = 0; k0 < K; k0 += 32){
    s16x8 a0 = ld8(pa0+k0), a1 = ld8(pa1+k0);
    s16x8 b0 = ld8(pb0+k0), b1 = ld8(pb1+k0);
    mfma_bf16(acc00,a0,b0); mfma_bf16(acc01,a0,b1);
    mfma_bf16(acc10,a1,b0); mfma_bf16(acc11,a1,b1);
  }
  accfence4(acc00, acc01, acc10, acc11);
  f32x4 accs[2][2] = {{acc00,acc01},{acc10,acc11}};
  int isf32 = flagp ? *flagp : 0;
#pragma unroll
  for (int m=0;m<2;m++){
#pragma unroll
    for (int n=0;n<2;n++){
      int col = colBase + n*16 + lr;
      float bv = bias ? b2f(bias[col]) : 0.f;
#pragma unroll
      for (int r=0;r<4;r++){
        int row = rowBase + m*16 + lk*4 + r;
        if (row < M){
          float v = accs[m][n][r] + bv;
          if (relu) v = fmaxf(v, 0.f);
          size_t idx = (size_t)row*N + col;
          if (resid_bf) v += b2f(resid_bf[idx]);
          if (resid_f)  v += resid_f[idx];
          if (out_f)  out_f[idx]  = v;
          if (out_bf) out_bf[idx] = f2b(v);
          if (flagp){ if (isf32) dev_f[idx] = v; else dev_bf[idx] = f2b(v); }
        }
      }
    }
  }
}

// ---------------- flash attention: 1 wave = 16 q-rows, tiles of 64 keys -----
__global__ __launch_bounds__(64) void flash_kernel(
    const u16* __restrict__ Qp, const u16* __restrict__ Kp, const u16* __restrict__ VTp,
    u16* __restrict__ out_bf, float* __restrict__ out_f,
    int M, int Nk, long q_hi_stride, long vt_hi_stride, int vt_ld, long o_hi_stride,
    float scale)
{
  int u = blockIdx.y, uh = u >> 2, ul = u & 3;
  const u16* q  = Qp  + (size_t)uh*q_hi_stride + ul*128;
  const u16* kk = Kp  + (size_t)uh*q_hi_stride + ul*128;
  const u16* vt = VTp + (size_t)uh*vt_hi_stride + (size_t)(ul*128)*vt_ld;
  size_t obase = (size_t)uh*o_hi_stride + ul*128;
  int lane = threadIdx.x, lr = lane & 15, lk = lane >> 4;
  int r0 = blockIdx.x*16;
  int qr = min(r0 + lr, M-1);
  s16x8 qf[4];
#pragma unroll
  for (int kd=0; kd<4; ++kd) qf[kd] = ld8(q + (size_t)qr*512 + kd*32 + lk*8);
  f32x4 oacc[8];
#pragma unroll
  for (int i=0;i<8;i++) oacc[i] = (f32x4){0,0,0,0};
  float mr[4] = {-1e30f,-1e30f,-1e30f,-1e30f};
  float ls[4] = {0,0,0,0};
  __shared__ u16 pls[16*80];
  int nkt = (Nk + 63) >> 6;
  for (int kt=0; kt<nkt; ++kt){
    int kb = kt*64;
    f32x4 s[4];
#pragma unroll
    for (int n=0;n<4;n++) s[n] = (f32x4){0,0,0,0};
#pragma unroll
    for (int n=0;n<4;n++){
      int kc = min(kb + n*16 + lr, Nk-1);
      const u16* kr = kk + (size_t)kc*512 + lk*8;
#pragma unroll
      for (int kd=0; kd<4; ++kd){
        s16x8 kf = ld8(kr + kd*32);
        mfma_bf16(s[n], qf[kd], kf);
      }
    }
    accfence4(s[0], s[1], s[2], s[3]);
    // scale + key mask
#pragma unroll
    for (int n=0;n<4;n++){
      bool valid = (kb + n*16 + lr) < Nk;
#pragma unroll
      for (int r=0;r<4;r++){
        float v2 = s[n][r]*scale;
        s[n][r] = valid ? v2 : -1e30f;
      }
    }
    float mx[4];
#pragma unroll
    for (int r=0;r<4;r++) mx[r] = fmaxf(fmaxf(s[0][r],s[1][r]), fmaxf(s[2][r],s[3][r]));
#pragma unroll
    for (int off=1; off<16; off<<=1){
#pragma unroll
      for (int r=0;r<4;r++) mx[r] = fmaxf(mx[r], __shfl_xor(mx[r], off, 64));
    }
    float al[4], rs[4];
#pragma unroll
    for (int r=0;r<4;r++){
      float mnew = fmaxf(mr[r], mx[r]);
      al[r] = __expf(mr[r]-mnew);
      mr[r] = mnew;
      rs[r] = 0.f;
    }
#pragma unroll
    for (int n=0;n<4;n++){
#pragma unroll
      for (int r=0;r<4;r++){
        float p = __expf(s[n][r]-mr[r]);
        rs[r] += p;
        pls[(lk*4+r)*80 + n*16 + lr] = f2b(p);
      }
    }
#pragma unroll
    for (int off=1; off<16; off<<=1){
#pragma unroll
      for (int r=0;r<4;r++) rs[r] += __shfl_xor(rs[r], off, 64);
    }
#pragma unroll
    for (int r=0;r<4;r++) ls[r] = ls[r]*al[r] + rs[r];
#pragma unroll
    for (int cf=0; cf<8; cf++){
#pragma unroll
      for (int r=0;r<4;r++) oacc[cf][r] *= al[r];
    }
    __syncthreads();
#pragma unroll
    for (int kd2=0; kd2<2; ++kd2){
      s16x8 pa = *(const s16x8*)(pls + lr*80 + kd2*32 + lk*8);
#pragma unroll
      for (int cf=0; cf<8; ++cf){
        s16x8 vb = ld8(vt + (size_t)(cf*16+lr)*vt_ld + kb + kd2*32 + lk*8);
        mfma_bf16(oacc[cf], pa, vb);
      }
    }
    __syncthreads();
  }
  accfence4(oacc[0], oacc[1], oacc[2], oacc[3]);
  accfence4(oacc[4], oacc[5], oacc[6], oacc[7]);
  float inv[4];
#pragma unroll
  for (int r=0;r<4;r++) inv[r] = 1.f/ls[r];
#pragma unroll
  for (int cf=0; cf<8; ++cf){
#pragma unroll
    for (int r=0;r<4;r++){
      int row = r0 + lk*4 + r;
      if (row < M){
        float o = oacc[cf][r]*inv[r];
        size_t idx = obase + (size_t)row*512 + cf*16 + lr;
        if (out_bf) out_bf[idx] = f2b(o);
        else        out_f[idx]  = o;
      }
    }
  }
}

// ---------------- tiled transpose: dst[c*dst_ld + r] = src[r*C + c], 0-pad --
__global__ void transpose_kernel(const u16* __restrict__ src, int R, int C,
                                 u16* __restrict__ dst, int dst_ld)
{
  __shared__ u16 tile[32][33];
  int r0 = blockIdx.x*32, c0 = blockIdx.y*32;
  int tx = threadIdx.x, ty = threadIdx.y;   // (32,8)
#pragma unroll
  for (int i=0;i<4;i++){
    int r = r0 + ty + i*8, c = c0 + tx;
    u16 v = 0;
    if (r < R && c < C) v = src[(size_t)r*C + c];
    tile[ty+i*8][tx] = v;
  }
  __syncthreads();
#pragma unroll
  for (int i=0;i<4;i++){
    int c = c0 + ty + i*8, r = r0 + tx;
    if (c < C && r < dst_ld) dst[(size_t)c*dst_ld + r] = tile[tx][ty+i*8];
  }
}

// ---------------- LayerNorm: one wave per 512-wide row ----------------------
__global__ __launch_bounds__(256) void ln_kernel(
    const u16* __restrict__ inb, const float* __restrict__ inf,
    const u16* __restrict__ gw, const u16* __restrict__ bw,
    u16* __restrict__ out, int rows)
{
  int w = threadIdx.x >> 6, lane = threadIdx.x & 63;
  int row = blockIdx.x*4 + w;
  if (row >= rows) return;
  float x[8];
  if (inb){
    s16x8 v = ld8(inb + (size_t)row*512 + lane*8);
#pragma unroll
    for (int j=0;j<8;j++) x[j] = b2f((u16)v[j]);
  } else {
    const float* p = inf + (size_t)row*512 + lane*8;
#pragma unroll
    for (int j=0;j<8;j++) x[j] = p[j];
  }
  float s = 0.f;
#pragma unroll
  for (int j=0;j<8;j++) s += x[j];
#pragma unroll
  for (int off=1; off<64; off<<=1) s += __shfl_xor(s, off, 64);
  float mean = s*(1.f/512.f);
  float vs = 0.f;
#pragma unroll
  for (int j=0;j<8;j++){ float d = x[j]-mean; vs += d*d; }
#pragma unroll
  for (int off=1; off<64; off<<=1) vs += __shfl_xor(vs, off, 64);
  float rstd = 1.f/sqrtf(vs*(1.f/512.f) + 1e-5f);
#pragma unroll
  for (int j=0;j<8;j++){
    int c = lane*8+j;
    float y = (x[j]-mean)*rstd*b2f(gw[c]) + b2f(bw[c]);
    out[(size_t)row*512 + c] = f2b(y);
  }
}

// ---------------- quadrant gather: xg[(g,l)] = x[n(g,l)] --------------------
__global__ __launch_bounds__(256) void gather_xg_kernel(const u16* __restrict__ x,
                                                        u16* __restrict__ xg)
{
  int w = threadIdx.x >> 6, lane = threadIdx.x & 63;
  int gl = blockIdx.x*4 + w;
  int g = gl/405, l = gl - g*405;
  int a = g >> 1, b = g & 1, hh = l/27, ww = l - hh*27;
  int n = a*810 + hh*54 + b*27 + ww;
  *(s16x8*)(xg + (size_t)gl*512 + lane*8) = *(const s16x8*)(x + (size_t)n*512 + lane*8);
}

// ---------------- xut = xa0 + mean_g ot[g][row%405] -------------------------
__global__ __launch_bounds__(256) void combine_kernel(const float* __restrict__ xa0,
                                                      const float* __restrict__ ot,
                                                      float* __restrict__ xut)
{
  int w = threadIdx.x >> 6, lane = threadIdx.x & 63;
  int row = blockIdx.x*4 + w;
  int l = row % 405;
  int c = lane*8;
  const float* pa = xa0 + (size_t)row*512 + c;
  float acc[8];
#pragma unroll
  for (int j=0;j<8;j++) acc[j] = pa[j];
#pragma unroll
  for (int g2=0; g2<4; ++g2){
    const float* po = ot + ((size_t)(g2*405+l))*512 + c;
#pragma unroll
    for (int j=0;j<8;j++) acc[j] += 0.25f*po[j];
  }
  float* pw = xut + (size_t)row*512 + c;
#pragma unroll
  for (int j=0;j<8;j++) pw[j] = acc[j];
}

// ---------------- mem_fin[0] = x verbatim (dtype-branched) ------------------
__global__ __launch_bounds__(256) void copy_out_kernel(
    const u16* __restrict__ s16, const float* __restrict__ s32,
    const int* __restrict__ flag, u16* __restrict__ dbf, float* __restrict__ df, int n8)
{
  int i = blockIdx.x*256 + threadIdx.x;
  if (i >= n8) return;
  if (*flag){
    ((f32x4*)df)[i*2]   = ((const f32x4*)s32)[i*2];
    ((f32x4*)df)[i*2+1] = ((const f32x4*)s32)[i*2+1];
  } else {
    ((s16x8*)dbf)[i] = ((const s16x8*)s16)[i];
  }
}

// ---------------------------------------------------------------------------
extern "C" void kernel_launch(void* const* d_in, const int* in_sizes, int n_in,
                              void* d_out, int out_size, void* d_ws, size_t ws_size,
                              hipStream_t stream)
{
  u16* outp16 = (u16*)d_out;
  float* outp32 = (float*)d_out;

  char* wsb = (char*)d_ws;
  size_t off = 0;
  auto alloc = [&](size_t bytes)->void*{
    void* p = wsb + off; off += (bytes + 255) & ~(size_t)255; return p; };

  int* flagp = (int*)alloc(256);

  // canonical bf16 copies of inputs (order matters; matches NormArgs)
  static const int din_idx[23] = {0, 2,3, 4,5, 6,7, 8,9, 10,11, 12,13,
                                  14,15, 16,17, 18,19, 20,21, 22,23};
  static const int din_n[23]   = {829440, 512,512, 262144,512, 262144,512,
                                  262144,512, 262144,512, 512,512,
                                  1048576,2048, 1048576,512, 512,512,
                                  1048576,2048, 1048576,512};
  NormArgs na;
  u16* cptr[23];
  int total = 0;
  for (int i=0;i<23;i++){ na.src[i] = d_in[din_idx[i]]; na.cumblk[i] = total/512; total += din_n[i]; }
  na.cumblk[23] = total/512;
  u16* canon = (u16*)alloc((size_t)total*2);
  { int c = 0; for (int i=0;i<23;i++){ cptr[i] = canon + c; c += din_n[i]; } }
  const u16 *cx=cptr[0], *cg1=cptr[1], *cb1=cptr[2],
            *cwq=cptr[3], *cbq=cptr[4], *cwk=cptr[5], *cbk=cptr[6],
            *cwv=cptr[7], *cbv=cptr[8], *cwo=cptr[9], *cbo=cptr[10],
            *cg2=cptr[11], *cb2=cptr[12], *cw1s=cptr[13], *cfb1s=cptr[14],
            *cw2s=cptr[15], *cfb2s=cptr[16], *ctg2=cptr[17], *ctb2=cptr[18],
            *cw1t=cptr[19], *cfb1t=cptr[20], *cw2t=cptr[21], *cfb2t=cptr[22];

  u16* wqT  = (u16*)alloc(512*512*2);
  u16* wkT  = (u16*)alloc(512*512*2);
  u16* wvT  = (u16*)alloc(512*512*2);
  u16* woT  = (u16*)alloc(512*512*2);
  u16* w1sT = (u16*)alloc(2048*512*2);
  u16* w2sT = (u16*)alloc(512*2048*2);
  u16* w1tT = (u16*)alloc(2048*512*2);
  u16* w2tT = (u16*)alloc(512*2048*2);
  u16* xn   = (u16*)alloc(1620*512*2);
  u16* qb   = (u16*)alloc(1620*512*2);
  u16* kbuf = (u16*)alloc(1620*512*2);
  u16* vbuf = (u16*)alloc(1620*512*2);
  u16* vT   = (u16*)alloc(512*1664*2);
  u16* attn = (u16*)alloc(1620*512*2);
  float* xu = (float*)alloc(1620*512*4);
  u16* yb   = (u16*)alloc(1620*512*2);
  u16* hh   = (u16*)alloc(1620*2048*2);
  float* xa0= (float*)alloc(1620*512*4);
  u16* xg   = (u16*)alloc(1620*512*2);
  u16* xgT  = (u16*)alloc(4*512*448*2);
  float* ot = (float*)alloc(4*405*512*4);
  float* xut= (float*)alloc(1620*512*4);
  u16* yt   = (u16*)alloc(1620*512*2);
  u16* ht   = (u16*)alloc(1620*2048*2);

  const float scale = 0.08838834764831843f;   // 1/sqrt(128)
  dim3 tb(32,8);

  // dtype detect + canonicalize
  detect_kernel<<<dim3(1), dim3(64), 0, stream>>>((const u16*)d_in[0], flagp);
  norm_kernel<<<dim3(total/512), dim3(64), 0, stream>>>(na, flagp, canon);

  // weight transposes (K,N) -> (N,K)
  transpose_kernel<<<dim3(16,16), tb, 0, stream>>>(cwq, 512, 512, wqT, 512);
  transpose_kernel<<<dim3(16,16), tb, 0, stream>>>(cwk, 512, 512, wkT, 512);
  transpose_kernel<<<dim3(16,16), tb, 0, stream>>>(cwv, 512, 512, wvT, 512);
  transpose_kernel<<<dim3(16,16), tb, 0, stream>>>(cwo, 512, 512, woT, 512);
  transpose_kernel<<<dim3(16,64), tb, 0, stream>>>(cw1s, 512, 2048, w1sT, 512);
  transpose_kernel<<<dim3(64,16), tb, 0, stream>>>(cw2s, 2048, 512, w2sT, 2048);
  transpose_kernel<<<dim3(16,64), tb, 0, stream>>>(cw1t, 512, 2048, w1tT, 512);
  transpose_kernel<<<dim3(64,16), tb, 0, stream>>>(cw2t, 2048, 512, w2tT, 2048);

  // spatial block (only t=0 of the concat survives)
  ln_kernel<<<dim3(405), dim3(256), 0, stream>>>(cx, nullptr, cg1, cb1, xn, 1620);
  gemm_kernel<<<dim3(8,26), dim3(256), 0, stream>>>(xn, wqT, cbq, 1620,512,512,
      nullptr,nullptr, qb, nullptr, nullptr,nullptr,nullptr, 0);
  gemm_kernel<<<dim3(8,26), dim3(256), 0, stream>>>(xn, wkT, cbk, 1620,512,512,
      nullptr,nullptr, kbuf, nullptr, nullptr,nullptr,nullptr, 0);
  gemm_kernel<<<dim3(8,26), dim3(256), 0, stream>>>(xn, wvT, cbv, 1620,512,512,
      nullptr,nullptr, vbuf, nullptr, nullptr,nullptr,nullptr, 0);
  transpose_kernel<<<dim3(52,16), tb, 0, stream>>>(vbuf, 1620, 512, vT, 1664);
  flash_kernel<<<dim3(102,4), dim3(64), 0, stream>>>(qb, kbuf, vT, attn, nullptr,
      1620, 1620, 0L, 0L, 1664, 0L, scale);
  gemm_kernel<<<dim3(8,26), dim3(256), 0, stream>>>(attn, woT, cbo, 1620,512,512,
      cx, nullptr, nullptr, xu, nullptr,nullptr,nullptr, 0);
  ln_kernel<<<dim3(405), dim3(256), 0, stream>>>(nullptr, xu, cg2, cb2, yb, 1620);
  gemm_kernel<<<dim3(32,26), dim3(256), 0, stream>>>(yb, w1sT, cfb1s, 1620,2048,512,
      nullptr,nullptr, hh, nullptr, nullptr,nullptr,nullptr, 1);
  // xa0 = xu + FFN; also write into mem_fin[1] region (dtype-branched)
  gemm_kernel<<<dim3(8,26), dim3(256), 0, stream>>>(hh, w2sT, cfb2s, 1620,512,2048,
      nullptr, xu, nullptr, xa0, flagp, outp16 + 1658880, outp32 + 1658880, 0);

  // temporal block (attention input is the ORIGINAL x, grouped by quadrant)
  gather_xg_kernel<<<dim3(405), dim3(256), 0, stream>>>(cx, xg);
  for (int g = 0; g < 4; ++g)
    transpose_kernel<<<dim3(14,16), tb, 0, stream>>>(xg + (size_t)g*405*512, 405, 512,
        xgT + (size_t)g*512*448, 448);
  flash_kernel<<<dim3(26,16), dim3(64), 0, stream>>>(xg, xg, xgT, nullptr, ot,
      405, 405, (long)(405*512), (long)(512*448), 448, (long)(405*512), scale);
  combine_kernel<<<dim3(405), dim3(256), 0, stream>>>(xa0, ot, xut);
  ln_kernel<<<dim3(405), dim3(256), 0, stream>>>(nullptr, xut, ctg2, ctb2, yt, 1620);
  gemm_kernel<<<dim3(32,26), dim3(256), 0, stream>>>(yt, w1tT, cfb1t, 1620,2048,512,
      nullptr,nullptr, ht, nullptr, nullptr,nullptr,nullptr, 1);
  gemm_kernel<<<dim3(8,26), dim3(256), 0, stream>>>(ht, w2tT, cfb2t, 1620,512,2048,
      nullptr, xut, nullptr, nullptr, flagp, outp16, outp32, 0);

  // mem_fin[0] = x verbatim
  copy_out_kernel<<<dim3(405), dim3(256), 0, stream>>>((const u16*)d_in[0],
      (const float*)d_in[0], flagp, outp16 + 829440, outp32 + 829440, 103680);
}

// Round 6
// 514.110 us; speedup vs baseline: 1.1549x; 1.1549x over previous
//
#include <hip/hip_runtime.h>
#include <stdint.h>

typedef unsigned short u16;
typedef float f32x4 __attribute__((ext_vector_type(4)));
typedef short s16x8 __attribute__((ext_vector_type(8)));

#define DEV __device__ __forceinline__

DEV float b2f(u16 u){ union{unsigned i; float f;} v; v.i = ((unsigned)u)<<16; return v.f; }
DEV u16 f2b(float f){ union{float f; unsigned i;} v; v.f=f; unsigned u=v.i;
                      return (u16)((u + 0x7FFFu + ((u>>16)&1u))>>16); }
DEV s16x8 ld8(const u16* p){ return *(const s16x8*)p; }

#define MFMA(d,a,b) d = __builtin_amdgcn_mfma_f32_16x16x32_bf16(a, b, d, 0, 0, 0)

// ---------------- dtype detection: f32 misread as bf16 has wild exponents ---
__global__ __launch_bounds__(64) void detect_kernel(const u16* __restrict__ x, int* flag){
  int lane = threadIdx.x;
  int cnt = 0;
  for (int i=0;i<32;i++){
    u16 v = x[lane*32+i];
    int e = (v >> 7) & 0xFF;
    if (e >= 0xE0) cnt++;           // |val| >= 2^97: impossible for N(0,1) bf16 data
  }
  for (int off=1; off<64; off<<=1) cnt += __shfl_xor(cnt, off, 64);
  if (lane==0) *flag = (cnt >= 16) ? 1 : 0;   // 1 = device buffers are f32
}

// ---------------- canonicalize all input tensors to contiguous bf16 ---------
struct NormArgs { const void* src[23]; int cumblk[24]; };

__global__ __launch_bounds__(64) void norm_kernel(NormArgs a, const int* __restrict__ flag,
                                                  u16* __restrict__ canon){
  int b = blockIdx.x, lane = threadIdx.x;
  int t = 0;
  while (t < 22 && b >= a.cumblk[t+1]) t++;
  int off = (b - a.cumblk[t])*512 + lane*8;
  size_t g = (size_t)b*512 + lane*8;
  if (*flag){
    const float* s = (const float*)a.src[t] + off;
    s16x8 o;
#pragma unroll
    for (int j=0;j<8;j++) o[j] = (short)f2b(s[j]);
    *(s16x8*)(canon+g) = o;
  } else {
    *(s16x8*)(canon+g) = *(const s16x8*)((const u16*)a.src[t] + off);
  }
}

// ---------------- MFMA GEMM: C = A(MxK) @ BT(NxK)^T + bias ------------------
// 8 waves / block, 64x64 tile, wave = 16 rows x 32 cols, direct global frags.
__global__ __launch_bounds__(512) void gemm_kernel(
    const u16* __restrict__ A, const u16* __restrict__ BT, const u16* __restrict__ bias,
    int M, int N, int K,
    const u16* __restrict__ resid_bf, const float* __restrict__ resid_f,
    u16* __restrict__ out_bf, float* __restrict__ out_f,
    const int* __restrict__ flagp, u16* __restrict__ dev_bf, float* __restrict__ dev_f,
    int relu)
{
  int tid = threadIdx.x, lane = tid & 63, wid = tid >> 6;
  int wm = wid & 3, wn = wid >> 2;
  int lr = lane & 15, lk = lane >> 4;
  int rowBase = blockIdx.y*64 + wm*16;
  int colBase = blockIdx.x*64 + wn*32;
  int ar  = min(rowBase + lr, M-1);
  int bc0 = colBase + lr, bc1 = colBase + 16 + lr;   // N is a multiple of 64
  const u16* pa  = A  + (size_t)ar*K  + lk*8;
  const u16* pb0 = BT + (size_t)bc0*K + lk*8;
  const u16* pb1 = BT + (size_t)bc1*K + lk*8;
  f32x4 acc0={0,0,0,0}, acc1={0,0,0,0};
#pragma unroll 4
  for (int k0 = 0; k0 < K; k0 += 32){
    s16x8 a  = ld8(pa+k0);
    s16x8 b0 = ld8(pb0+k0), b1 = ld8(pb1+k0);
    MFMA(acc0, a, b0);
    MFMA(acc1, a, b1);
  }
  f32x4 accs[2] = {acc0, acc1};
  int isf32 = flagp ? *flagp : 0;
#pragma unroll
  for (int n=0;n<2;n++){
    int col = colBase + n*16 + lr;
    float bv = bias ? b2f(bias[col]) : 0.f;
#pragma unroll
    for (int r=0;r<4;r++){
      int row = rowBase + lk*4 + r;
      if (row < M){
        float v = accs[n][r] + bv;
        if (relu) v = fmaxf(v, 0.f);
        size_t idx = (size_t)row*N + col;
        if (resid_bf) v += b2f(resid_bf[idx]);
        if (resid_f)  v += resid_f[idx];
        if (out_f)  out_f[idx]  = v;
        if (out_bf) out_bf[idx] = f2b(v);
        if (flagp){ if (isf32) dev_f[idx] = v; else dev_bf[idx] = f2b(v); }
      }
    }
  }
}

// ---------------- partial flash: 1 wave = 16 q-rows x one key-chunk ---------
// Writes unnormalized o (f32), running max m, running sum l per q-row.
// po layout: [unit][chunk][row][128]; pm/pl: [unit][chunk][row].
__global__ __launch_bounds__(64) void flashp_kernel(
    const u16* __restrict__ Qp, const u16* __restrict__ Kp, const u16* __restrict__ VTp,
    float* __restrict__ po, float* __restrict__ pm, float* __restrict__ pl,
    int M, int Nk, int tiles_total, int nchunks,
    long q_hi_stride, long vt_hi_stride, int vt_ld, float scale)
{
  int u = blockIdx.y, c = blockIdx.z;
  int uh = u >> 2, ul = u & 3;
  const u16* q  = Qp  + (size_t)uh*q_hi_stride + ul*128;
  const u16* kk = Kp  + (size_t)uh*q_hi_stride + ul*128;
  const u16* vt = VTp + (size_t)uh*vt_hi_stride + (size_t)(ul*128)*vt_ld;
  int lane = threadIdx.x, lr = lane & 15, lk = lane >> 4;
  int r0 = blockIdx.x*16;
  int qr = min(r0 + lr, M-1);
  s16x8 qf[4];
#pragma unroll
  for (int kd=0; kd<4; ++kd) qf[kd] = ld8(q + (size_t)qr*512 + kd*32 + lk*8);
  f32x4 oacc[8];
#pragma unroll
  for (int i=0;i<8;i++) oacc[i] = (f32x4){0,0,0,0};
  float mr[4] = {-1e30f,-1e30f,-1e30f,-1e30f};
  float ls[4] = {0,0,0,0};
  __shared__ u16 plsm[16*80];
  int t0 = (tiles_total * c) / nchunks;
  int t1 = (tiles_total * (c+1)) / nchunks;
  for (int kt=t0; kt<t1; ++kt){
    int kb = kt*64;
    // batched K-fragment loads (16 independent 16B/lane loads -> one wait)
    s16x8 kf[16];
#pragma unroll
    for (int n=0;n<4;n++){
      int kc = min(kb + n*16 + lr, Nk-1);
      const u16* kr = kk + (size_t)kc*512 + lk*8;
#pragma unroll
      for (int kd=0; kd<4; ++kd) kf[n*4+kd] = ld8(kr + kd*32);
    }
    f32x4 s[4];
#pragma unroll
    for (int n=0;n<4;n++) s[n] = (f32x4){0,0,0,0};
#pragma unroll
    for (int n=0;n<4;n++)
#pragma unroll
      for (int kd=0; kd<4; ++kd)
        MFMA(s[n], qf[kd], kf[n*4+kd]);
    // scale + key mask
#pragma unroll
    for (int n=0;n<4;n++){
      bool valid = (kb + n*16 + lr) < Nk;
#pragma unroll
      for (int r=0;r<4;r++){
        float v2 = s[n][r]*scale;
        s[n][r] = valid ? v2 : -1e30f;
      }
    }
    float mx[4];
#pragma unroll
    for (int r=0;r<4;r++) mx[r] = fmaxf(fmaxf(s[0][r],s[1][r]), fmaxf(s[2][r],s[3][r]));
#pragma unroll
    for (int off=1; off<16; off<<=1){
#pragma unroll
      for (int r=0;r<4;r++) mx[r] = fmaxf(mx[r], __shfl_xor(mx[r], off, 64));
    }
    float al[4], rs[4];
#pragma unroll
    for (int r=0;r<4;r++){
      float mnew = fmaxf(mr[r], mx[r]);
      al[r] = __expf(mr[r]-mnew);
      mr[r] = mnew;
      rs[r] = 0.f;
    }
#pragma unroll
    for (int n=0;n<4;n++){
#pragma unroll
      for (int r=0;r<4;r++){
        float p = __expf(s[n][r]-mr[r]);
        rs[r] += p;
        plsm[(lk*4+r)*80 + n*16 + lr] = f2b(p);
      }
    }
#pragma unroll
    for (int off=1; off<16; off<<=1){
#pragma unroll
      for (int r=0;r<4;r++) rs[r] += __shfl_xor(rs[r], off, 64);
    }
#pragma unroll
    for (int r=0;r<4;r++) ls[r] = ls[r]*al[r] + rs[r];
#pragma unroll
    for (int cf=0; cf<8; cf++){
#pragma unroll
      for (int r=0;r<4;r++) oacc[cf][r] *= al[r];
    }
    __syncthreads();
#pragma unroll
    for (int kd2=0; kd2<2; ++kd2){
      s16x8 pa = *(const s16x8*)(plsm + lr*80 + kd2*32 + lk*8);
#pragma unroll
      for (int cf=0; cf<8; ++cf){
        s16x8 vb = ld8(vt + (size_t)(cf*16+lr)*vt_ld + kb + kd2*32 + lk*8);
        MFMA(oacc[cf], pa, vb);
      }
    }
    __syncthreads();
  }
  // write partials (unnormalized)
  size_t pbase = ((size_t)u*nchunks + c)*M;
#pragma unroll
  for (int cf=0; cf<8; ++cf){
#pragma unroll
    for (int r=0;r<4;r++){
      int row = r0 + lk*4 + r;
      if (row < M) po[(pbase + row)*128 + cf*16 + lr] = oacc[cf][r];
    }
  }
  if (lr == 0){
#pragma unroll
    for (int r=0;r<4;r++){
      int row = r0 + lk*4 + r;
      if (row < M){ pm[pbase + row] = mr[r]; pl[pbase + row] = ls[r]; }
    }
  }
}

// ---------------- flash combine: merge K-chunks, normalize ------------------
__global__ __launch_bounds__(256) void fcomb_kernel(
    const float* __restrict__ po, const float* __restrict__ pm, const float* __restrict__ pl,
    u16* __restrict__ out_bf, float* __restrict__ out_f,
    int rows, int nunits, int nchunks, long o_hi_stride)
{
  int w = threadIdx.x >> 6, lane = threadIdx.x & 63;
  int gid = blockIdx.x*4 + w;
  if (gid >= nunits*rows) return;
  int u = gid / rows, row = gid - u*rows;
  size_t pb = (size_t)u*nchunks*rows + row;
  float m = -1e30f;
  for (int c=0;c<nchunks;c++) m = fmaxf(m, pm[pb + (size_t)c*rows]);
  float L = 0.f, o0 = 0.f, o1 = 0.f;
  for (int c=0;c<nchunks;c++){
    float wgt = __expf(pm[pb + (size_t)c*rows] - m);
    L += wgt * pl[pb + (size_t)c*rows];
    const float* op = po + (pb + (size_t)c*rows)*128;
    o0 += wgt * op[lane*2];
    o1 += wgt * op[lane*2+1];
  }
  float inv = 1.f/L;
  int uh = u>>2, ul = u&3;
  size_t idx = (size_t)uh*o_hi_stride + (size_t)row*512 + ul*128 + lane*2;
  if (out_bf){ out_bf[idx] = f2b(o0*inv); out_bf[idx+1] = f2b(o1*inv); }
  else       { out_f[idx]  = o0*inv;      out_f[idx+1]  = o1*inv; }
}

// ---------------- tiled transpose: dst[c*dst_ld + r] = src[r*C + c], 0-pad --
__global__ void transpose_kernel(const u16* __restrict__ src, int R, int C,
                                 u16* __restrict__ dst, int dst_ld)
{
  __shared__ u16 tile[32][33];
  int r0 = blockIdx.x*32, c0 = blockIdx.y*32;
  int tx = threadIdx.x, ty = threadIdx.y;   // (32,8)
#pragma unroll
  for (int i=0;i<4;i++){
    int r = r0 + ty + i*8, c = c0 + tx;
    u16 v = 0;
    if (r < R && c < C) v = src[(size_t)r*C + c];
    tile[ty+i*8][tx] = v;
  }
  __syncthreads();
#pragma unroll
  for (int i=0;i<4;i++){
    int c = c0 + ty + i*8, r = r0 + tx;
    if (c < C && r < dst_ld) dst[(size_t)c*dst_ld + r] = tile[tx][ty+i*8];
  }
}

// ---------------- LayerNorm: one wave per 512-wide row ----------------------
__global__ __launch_bounds__(256) void ln_kernel(
    const u16* __restrict__ inb, const float* __restrict__ inf,
    const u16* __restrict__ gw, const u16* __restrict__ bw,
    u16* __restrict__ out, int rows)
{
  int w = threadIdx.x >> 6, lane = threadIdx.x & 63;
  int row = blockIdx.x*4 + w;
  if (row >= rows) return;
  float x[8];
  if (inb){
    s16x8 v = ld8(inb + (size_t)row*512 + lane*8);
#pragma unroll
    for (int j=0;j<8;j++) x[j] = b2f((u16)v[j]);
  } else {
    const float* p = inf + (size_t)row*512 + lane*8;
#pragma unroll
    for (int j=0;j<8;j++) x[j] = p[j];
  }
  float s = 0.f;
#pragma unroll
  for (int j=0;j<8;j++) s += x[j];
#pragma unroll
  for (int off=1; off<64; off<<=1) s += __shfl_xor(s, off, 64);
  float mean = s*(1.f/512.f);
  float vs = 0.f;
#pragma unroll
  for (int j=0;j<8;j++){ float d = x[j]-mean; vs += d*d; }
#pragma unroll
  for (int off=1; off<64; off<<=1) vs += __shfl_xor(vs, off, 64);
  float rstd = 1.f/sqrtf(vs*(1.f/512.f) + 1e-5f);
#pragma unroll
  for (int j=0;j<8;j++){
    int c = lane*8+j;
    float y = (x[j]-mean)*rstd*b2f(gw[c]) + b2f(bw[c]);
    out[(size_t)row*512 + c] = f2b(y);
  }
}

// ---------------- quadrant gather: xg[(g,l)] = x[n(g,l)] --------------------
__global__ __launch_bounds__(256) void gather_xg_kernel(const u16* __restrict__ x,
                                                        u16* __restrict__ xg)
{
  int w = threadIdx.x >> 6, lane = threadIdx.x & 63;
  int gl = blockIdx.x*4 + w;
  int g = gl/405, l = gl - g*405;
  int a = g >> 1, b = g & 1, hh = l/27, ww = l - hh*27;
  int n = a*810 + hh*54 + b*27 + ww;
  *(s16x8*)(xg + (size_t)gl*512 + lane*8) = *(const s16x8*)(x + (size_t)n*512 + lane*8);
}

// ---------------- xut = xa0 + mean_g ot[g][row%405] -------------------------
__global__ __launch_bounds__(256) void combine_kernel(const float* __restrict__ xa0,
                                                      const float* __restrict__ ot,
                                                      float* __restrict__ xut)
{
  int w = threadIdx.x >> 6, lane = threadIdx.x & 63;
  int row = blockIdx.x*4 + w;
  int l = row % 405;
  int c = lane*8;
  const float* pa = xa0 + (size_t)row*512 + c;
  float acc[8];
#pragma unroll
  for (int j=0;j<8;j++) acc[j] = pa[j];
#pragma unroll
  for (int g2=0; g2<4; ++g2){
    const float* po = ot + ((size_t)(g2*405+l))*512 + c;
#pragma unroll
    for (int j=0;j<8;j++) acc[j] += 0.25f*po[j];
  }
  float* pw = xut + (size_t)row*512 + c;
#pragma unroll
  for (int j=0;j<8;j++) pw[j] = acc[j];
}

// ---------------- mem_fin[0] = x verbatim (dtype-branched) ------------------
__global__ __launch_bounds__(256) void copy_out_kernel(
    const u16* __restrict__ s16, const float* __restrict__ s32,
    const int* __restrict__ flag, u16* __restrict__ dbf, float* __restrict__ df, int n8)
{
  int i = blockIdx.x*256 + threadIdx.x;
  if (i >= n8) return;
  if (*flag){
    ((f32x4*)df)[i*2]   = ((const f32x4*)s32)[i*2];
    ((f32x4*)df)[i*2+1] = ((const f32x4*)s32)[i*2+1];
  } else {
    ((s16x8*)dbf)[i] = ((const s16x8*)s16)[i];
  }
}

// ---------------------------------------------------------------------------
extern "C" void kernel_launch(void* const* d_in, const int* in_sizes, int n_in,
                              void* d_out, int out_size, void* d_ws, size_t ws_size,
                              hipStream_t stream)
{
  u16* outp16 = (u16*)d_out;
  float* outp32 = (float*)d_out;

  char* wsb = (char*)d_ws;
  size_t off = 0;
  auto alloc = [&](size_t bytes)->void*{
    void* p = wsb + off; off += (bytes + 255) & ~(size_t)255; return p; };

  int* flagp = (int*)alloc(256);

  // canonical bf16 copies of inputs (order matters; matches NormArgs)
  static const int din_idx[23] = {0, 2,3, 4,5, 6,7, 8,9, 10,11, 12,13,
                                  14,15, 16,17, 18,19, 20,21, 22,23};
  static const int din_n[23]   = {829440, 512,512, 262144,512, 262144,512,
                                  262144,512, 262144,512, 512,512,
                                  1048576,2048, 1048576,512, 512,512,
                                  1048576,2048, 1048576,512};
  NormArgs na;
  u16* cptr[23];
  int total = 0;
  for (int i=0;i<23;i++){ na.src[i] = d_in[din_idx[i]]; na.cumblk[i] = total/512; total += din_n[i]; }
  na.cumblk[23] = total/512;
  u16* canon = (u16*)alloc((size_t)total*2);
  { int c = 0; for (int i=0;i<23;i++){ cptr[i] = canon + c; c += din_n[i]; } }
  const u16 *cx=cptr[0], *cg1=cptr[1], *cb1=cptr[2],
            *cwq=cptr[3], *cbq=cptr[4], *cwk=cptr[5], *cbk=cptr[6],
            *cwv=cptr[7], *cbv=cptr[8], *cwo=cptr[9], *cbo=cptr[10],
            *cg2=cptr[11], *cb2=cptr[12], *cw1s=cptr[13], *cfb1s=cptr[14],
            *cw2s=cptr[15], *cfb2s=cptr[16], *ctg2=cptr[17], *ctb2=cptr[18],
            *cw1t=cptr[19], *cfb1t=cptr[20], *cw2t=cptr[21], *cfb2t=cptr[22];

  u16* wqT  = (u16*)alloc(512*512*2);
  u16* wkT  = (u16*)alloc(512*512*2);
  u16* wvT  = (u16*)alloc(512*512*2);
  u16* woT  = (u16*)alloc(512*512*2);
  u16* w1sT = (u16*)alloc(2048*512*2);
  u16* w2sT = (u16*)alloc(512*2048*2);
  u16* w1tT = (u16*)alloc(2048*512*2);
  u16* w2tT = (u16*)alloc(512*2048*2);
  u16* xn   = (u16*)alloc(1620*512*2);
  u16* qb   = (u16*)alloc(1620*512*2);
  u16* kbuf = (u16*)alloc(1620*512*2);
  u16* vbuf = (u16*)alloc(1620*512*2);
  u16* vT   = (u16*)alloc(512*1664*2);
  u16* attn = (u16*)alloc(1620*512*2);
  float* xu = (float*)alloc(1620*512*4);
  u16* yb   = (u16*)alloc(1620*512*2);
  u16* hh   = (u16*)alloc(1620*2048*2);
  float* xa0= (float*)alloc(1620*512*4);
  u16* xg   = (u16*)alloc(1620*512*2);
  u16* xgT  = (u16*)alloc(4*512*448*2);
  float* ot = (float*)alloc(4*405*512*4);
  float* xut= (float*)alloc(1620*512*4);
  u16* yt   = (u16*)alloc(1620*512*2);
  u16* ht   = (u16*)alloc(1620*2048*2);
  // flash partial buffers (max of spatial 4u*4c*1620r, temporal 16u*2c*405r)
  float* po = (float*)alloc((size_t)4*4*1620*128*4);
  float* pm = (float*)alloc((size_t)4*4*1620*4);
  float* pl = (float*)alloc((size_t)4*4*1620*4);

  const float scale = 0.08838834764831843f;   // 1/sqrt(128)
  dim3 tb(32,8);

  // dtype detect + canonicalize
  detect_kernel<<<dim3(1), dim3(64), 0, stream>>>((const u16*)d_in[0], flagp);
  norm_kernel<<<dim3(total/512), dim3(64), 0, stream>>>(na, flagp, canon);

  // weight transposes (K,N) -> (N,K)
  transpose_kernel<<<dim3(16,16), tb, 0, stream>>>(cwq, 512, 512, wqT, 512);
  transpose_kernel<<<dim3(16,16), tb, 0, stream>>>(cwk, 512, 512, wkT, 512);
  transpose_kernel<<<dim3(16,16), tb, 0, stream>>>(cwv, 512, 512, wvT, 512);
  transpose_kernel<<<dim3(16,16), tb, 0, stream>>>(cwo, 512, 512, woT, 512);
  transpose_kernel<<<dim3(16,64), tb, 0, stream>>>(cw1s, 512, 2048, w1sT, 512);
  transpose_kernel<<<dim3(64,16), tb, 0, stream>>>(cw2s, 2048, 512, w2sT, 2048);
  transpose_kernel<<<dim3(16,64), tb, 0, stream>>>(cw1t, 512, 2048, w1tT, 512);
  transpose_kernel<<<dim3(64,16), tb, 0, stream>>>(cw2t, 2048, 512, w2tT, 2048);

  // spatial block (only t=0 of the concat survives)
  ln_kernel<<<dim3(405), dim3(256), 0, stream>>>(cx, nullptr, cg1, cb1, xn, 1620);
  gemm_kernel<<<dim3(8,26), dim3(512), 0, stream>>>(xn, wqT, cbq, 1620,512,512,
      nullptr,nullptr, qb, nullptr, nullptr,nullptr,nullptr, 0);
  gemm_kernel<<<dim3(8,26), dim3(512), 0, stream>>>(xn, wkT, cbk, 1620,512,512,
      nullptr,nullptr, kbuf, nullptr, nullptr,nullptr,nullptr, 0);
  gemm_kernel<<<dim3(8,26), dim3(512), 0, stream>>>(xn, wvT, cbv, 1620,512,512,
      nullptr,nullptr, vbuf, nullptr, nullptr,nullptr,nullptr, 0);
  transpose_kernel<<<dim3(52,16), tb, 0, stream>>>(vbuf, 1620, 512, vT, 1664);
  // spatial flash: 102 q-tiles x 4 heads x 4 key-chunks (26 tiles split 6/7/6/7)
  flashp_kernel<<<dim3(102,4,4), dim3(64), 0, stream>>>(qb, kbuf, vT, po, pm, pl,
      1620, 1620, 26, 4, 0L, 0L, 1664, scale);
  fcomb_kernel<<<dim3(1620), dim3(256), 0, stream>>>(po, pm, pl, attn, nullptr,
      1620, 4, 4, 0L);
  gemm_kernel<<<dim3(8,26), dim3(512), 0, stream>>>(attn, woT, cbo, 1620,512,512,
      cx, nullptr, nullptr, xu, nullptr,nullptr,nullptr, 0);
  ln_kernel<<<dim3(405), dim3(256), 0, stream>>>(nullptr, xu, cg2, cb2, yb, 1620);
  gemm_kernel<<<dim3(32,26), dim3(512), 0, stream>>>(yb, w1sT, cfb1s, 1620,2048,512,
      nullptr,nullptr, hh, nullptr, nullptr,nullptr,nullptr, 1);
  // xa0 = xu + FFN; also write into mem_fin[1] region (dtype-branched)
  gemm_kernel<<<dim3(8,26), dim3(512), 0, stream>>>(hh, w2sT, cfb2s, 1620,512,2048,
      nullptr, xu, nullptr, xa0, flagp, outp16 + 1658880, outp32 + 1658880, 0);

  // temporal block (attention input is the ORIGINAL x, grouped by quadrant)
  gather_xg_kernel<<<dim3(405), dim3(256), 0, stream>>>(cx, xg);
  for (int g = 0; g < 4; ++g)
    transpose_kernel<<<dim3(14,16), tb, 0, stream>>>(xg + (size_t)g*405*512, 405, 512,
        xgT + (size_t)g*512*448, 448);
  // temporal flash: 26 q-tiles x 16 (g,h) units x 2 key-chunks (7 tiles: 3/4)
  flashp_kernel<<<dim3(26,16,2), dim3(64), 0, stream>>>(xg, xg, xgT, po, pm, pl,
      405, 405, 7, 2, (long)(405*512), (long)(512*448), 448, scale);
  fcomb_kernel<<<dim3(1620), dim3(256), 0, stream>>>(po, pm, pl, nullptr, ot,
      405, 16, 2, (long)(405*512));
  combine_kernel<<<dim3(405), dim3(256), 0, stream>>>(xa0, ot, xut);
  ln_kernel<<<dim3(405), dim3(256), 0, stream>>>(nullptr, xut, ctg2, ctb2, yt, 1620);
  gemm_kernel<<<dim3(32,26), dim3(512), 0, stream>>>(yt, w1tT, cfb1t, 1620,2048,512,
      nullptr,nullptr, ht, nullptr, nullptr,nullptr,nullptr, 1);
  gemm_kernel<<<dim3(8,26), dim3(512), 0, stream>>>(ht, w2tT, cfb2t, 1620,512,2048,
      nullptr, xut, nullptr, nullptr, flagp, outp16, outp32, 0);

  // mem_fin[0] = x verbatim
  copy_out_kernel<<<dim3(405), dim3(256), 0, stream>>>((const u16*)d_in[0],
      (const float*)d_in[0], flagp, outp16 + 829440, outp32 + 829440, 103680);
}

// Round 7
// 500.132 us; speedup vs baseline: 1.1872x; 1.0279x over previous
//
#include <hip/hip_runtime.h>
#include <stdint.h>

typedef unsigned short u16;
typedef float f32x4 __attribute__((ext_vector_type(4)));
typedef short s16x8 __attribute__((ext_vector_type(8)));

#define DEV __device__ __forceinline__

DEV float b2f(u16 u){ union{unsigned i; float f;} v; v.i = ((unsigned)u)<<16; return v.f; }
DEV u16 f2b(float f){ union{float f; unsigned i;} v; v.f=f; unsigned u=v.i;
                      return (u16)((u + 0x7FFFu + ((u>>16)&1u))>>16); }
DEV s16x8 ld8(const u16* p){ return *(const s16x8*)p; }

#define MFMA(d,a,b) d = __builtin_amdgcn_mfma_f32_16x16x32_bf16(a, b, d, 0, 0, 0)

// ---------------- dtype detection: f32 misread as bf16 has wild exponents ---
__global__ __launch_bounds__(64) void detect_kernel(const u16* __restrict__ x, int* flag){
  int lane = threadIdx.x;
  int cnt = 0;
  for (int i=0;i<32;i++){
    u16 v = x[lane*32+i];
    int e = (v >> 7) & 0xFF;
    if (e >= 0xE0) cnt++;           // |val| >= 2^97: impossible for N(0,1) bf16 data
  }
  for (int off=1; off<64; off<<=1) cnt += __shfl_xor(cnt, off, 64);
  if (lane==0) *flag = (cnt >= 16) ? 1 : 0;   // 1 = device buffers are f32
}

// ---------------- canonicalize all input tensors to contiguous bf16 ---------
struct NormArgs { const void* src[23]; int cumblk[24]; };

__global__ __launch_bounds__(64) void norm_kernel(NormArgs a, const int* __restrict__ flag,
                                                  u16* __restrict__ canon){
  int b = blockIdx.x, lane = threadIdx.x;
  int t = 0;
  while (t < 22 && b >= a.cumblk[t+1]) t++;
  int off = (b - a.cumblk[t])*512 + lane*8;
  size_t g = (size_t)b*512 + lane*8;
  if (*flag){
    const float* s = (const float*)a.src[t] + off;
    s16x8 o;
#pragma unroll
    for (int j=0;j<8;j++) o[j] = (short)f2b(s[j]);
    *(s16x8*)(canon+g) = o;
  } else {
    *(s16x8*)(canon+g) = *(const s16x8*)((const u16*)a.src[t] + off);
  }
}

// ---------------- batched tiled transpose (job table) -----------------------
// dst[c*dstld + r] = src[r*srcld + c]; r guarded by R (load, 0-fill) and dstld.
struct TJobs {
  const u16* src[8]; u16* dst[8];
  int R[8], C32[8], srcld[8], dstld[8];
  int cum[9];
};
__global__ void trans_kernel(TJobs J){
  int b = blockIdx.x;
  int t = 0;
  while (b >= J.cum[t+1]) t++;
  int idx = b - J.cum[t];
  int tr = idx / J.C32[t], tc = idx - tr*J.C32[t];
  int r0 = tr*32, c0 = tc*32;
  const u16* src = J.src[t];
  u16* dst = J.dst[t];
  int R = J.R[t], srcld = J.srcld[t], dstld = J.dstld[t];
  __shared__ u16 tile[32][33];
  int tx = threadIdx.x, ty = threadIdx.y;   // (32,8)
#pragma unroll
  for (int i=0;i<4;i++){
    int r = r0 + ty + i*8, c = c0 + tx;
    u16 v = 0;
    if (r < R) v = src[(size_t)r*srcld + c];
    tile[ty+i*8][tx] = v;
  }
  __syncthreads();
#pragma unroll
  for (int i=0;i<4;i++){
    int c = c0 + ty + i*8, r = r0 + tx;
    if (r < dstld) dst[(size_t)c*dstld + r] = tile[tx][ty+i*8];
  }
}

// ---------------- MFMA GEMM: C = A(MxK) @ BT(NxK)^T + bias ------------------
// 8 waves / block, 64x64 tile, wave = 16 rows x 32 cols, direct global frags.
// bias2/bias3: QKV mode (bias per 512-col segment).
__global__ __launch_bounds__(512) void gemm_kernel(
    const u16* __restrict__ A, const u16* __restrict__ BT,
    const u16* __restrict__ bias, const u16* __restrict__ bias2, const u16* __restrict__ bias3,
    int M, int N, int K,
    const u16* __restrict__ resid_bf, const float* __restrict__ resid_f,
    u16* __restrict__ out_bf, float* __restrict__ out_f,
    const int* __restrict__ flagp, u16* __restrict__ dev_bf, float* __restrict__ dev_f,
    int relu)
{
  int tid = threadIdx.x, lane = tid & 63, wid = tid >> 6;
  int wm = wid & 3, wn = wid >> 2;
  int lr = lane & 15, lk = lane >> 4;
  int rowBase = blockIdx.y*64 + wm*16;
  int colBase = blockIdx.x*64 + wn*32;
  int ar  = min(rowBase + lr, M-1);
  int bc0 = colBase + lr, bc1 = colBase + 16 + lr;   // N is a multiple of 64
  const u16* pa  = A  + (size_t)ar*K  + lk*8;
  const u16* pb0 = BT + (size_t)bc0*K + lk*8;
  const u16* pb1 = BT + (size_t)bc1*K + lk*8;
  f32x4 acc0={0,0,0,0}, acc1={0,0,0,0};
#pragma unroll 4
  for (int k0 = 0; k0 < K; k0 += 32){
    s16x8 a  = ld8(pa+k0);
    s16x8 b0 = ld8(pb0+k0), b1 = ld8(pb1+k0);
    MFMA(acc0, a, b0);
    MFMA(acc1, a, b1);
  }
  f32x4 accs[2] = {acc0, acc1};
  int isf32 = flagp ? *flagp : 0;
#pragma unroll
  for (int n=0;n<2;n++){
    int col = colBase + n*16 + lr;
    float bv = 0.f;
    if (bias){
      if (bias2){
        const u16* bp = (col < 512) ? bias : ((col < 1024) ? bias2 : bias3);
        bv = b2f(bp[col & 511]);
      } else bv = b2f(bias[col]);
    }
#pragma unroll
    for (int r=0;r<4;r++){
      int row = rowBase + lk*4 + r;
      if (row < M){
        float v = accs[n][r] + bv;
        if (relu) v = fmaxf(v, 0.f);
        size_t idx = (size_t)row*N + col;
        if (resid_bf) v += b2f(resid_bf[idx]);
        if (resid_f)  v += resid_f[idx];
        if (out_f)  out_f[idx]  = v;
        if (out_bf) out_bf[idx] = f2b(v);
        if (flagp){ if (isf32) dev_f[idx] = v; else dev_bf[idx] = f2b(v); }
      }
    }
  }
}

// ---------------- split-K GEMM partial: pout[z][M][N] (f32, no epilogue) ----
__global__ __launch_bounds__(512) void gemm_splitk_kernel(
    const u16* __restrict__ A, const u16* __restrict__ BT,
    int M, int N, int K, int KS, float* __restrict__ pout)
{
  int tid = threadIdx.x, lane = tid & 63, wid = tid >> 6;
  int wm = wid & 3, wn = wid >> 2;
  int lr = lane & 15, lk = lane >> 4;
  int z = blockIdx.z;
  int kA = (K*z)/KS, kB = (K*(z+1))/KS;
  int rowBase = blockIdx.y*64 + wm*16;
  int colBase = blockIdx.x*64 + wn*32;
  int ar  = min(rowBase + lr, M-1);
  int bc0 = colBase + lr, bc1 = colBase + 16 + lr;
  const u16* pa  = A  + (size_t)ar*K  + lk*8;
  const u16* pb0 = BT + (size_t)bc0*K + lk*8;
  const u16* pb1 = BT + (size_t)bc1*K + lk*8;
  f32x4 acc0={0,0,0,0}, acc1={0,0,0,0};
#pragma unroll 4
  for (int k0 = kA; k0 < kB; k0 += 32){
    s16x8 a  = ld8(pa+k0);
    s16x8 b0 = ld8(pb0+k0), b1 = ld8(pb1+k0);
    MFMA(acc0, a, b0);
    MFMA(acc1, a, b1);
  }
  f32x4 accs[2] = {acc0, acc1};
  float* pz = pout + (size_t)z*M*N;
#pragma unroll
  for (int n=0;n<2;n++){
    int col = colBase + n*16 + lr;
#pragma unroll
    for (int r=0;r<4;r++){
      int row = rowBase + lk*4 + r;
      if (row < M) pz[(size_t)row*N + col] = accs[n][r];
    }
  }
}

// ---------------- split-K combine + epilogue (N=512) ------------------------
__global__ __launch_bounds__(256) void gemm_comb_kernel(
    const float* __restrict__ pout, int KS, const u16* __restrict__ bias,
    int M, int N, int relu,
    const u16* __restrict__ resid_bf, const float* __restrict__ resid_f,
    u16* __restrict__ out_bf, float* __restrict__ out_f,
    const int* __restrict__ flagp, u16* __restrict__ dev_bf, float* __restrict__ dev_f)
{
  int w = threadIdx.x >> 6, lane = threadIdx.x & 63;
  int row = blockIdx.x*4 + w;
  if (row >= M) return;
  int c0 = lane*8;
  float acc[8];
  const float* p0 = pout + (size_t)row*N + c0;
#pragma unroll
  for (int j=0;j<8;j++) acc[j] = p0[j];
  for (int z=1; z<KS; ++z){
    const float* pz = pout + ((size_t)z*M + row)*N + c0;
#pragma unroll
    for (int j=0;j<8;j++) acc[j] += pz[j];
  }
  int isf32 = flagp ? *flagp : 0;
#pragma unroll
  for (int j=0;j<8;j++){
    int col = c0 + j;
    float v = acc[j] + (bias ? b2f(bias[col]) : 0.f);
    if (relu) v = fmaxf(v, 0.f);
    size_t idx = (size_t)row*N + col;
    if (resid_bf) v += b2f(resid_bf[idx]);
    if (resid_f)  v += resid_f[idx];
    if (out_f)  out_f[idx]  = v;
    if (out_bf) out_bf[idx] = f2b(v);
    if (flagp){ if (isf32) dev_f[idx] = v; else dev_bf[idx] = f2b(v); }
  }
}

// ---------------- partial flash: 1 wave = 16 q-rows x one key-chunk ---------
// po layout: [unit][chunk][row][128]; pm/pl: [unit][chunk][row].
__global__ __launch_bounds__(64) void flashp_kernel(
    const u16* __restrict__ Qp, const u16* __restrict__ Kp, const u16* __restrict__ VTp,
    float* __restrict__ po, float* __restrict__ pm, float* __restrict__ pl,
    int M, int Nk, int qld, int tiles_total, int nchunks,
    long q_hi_stride, long vt_hi_stride, int vt_ld, float scale)
{
  int u = blockIdx.y, c = blockIdx.z;
  int uh = u >> 2, ul = u & 3;
  const u16* q  = Qp  + (size_t)uh*q_hi_stride + ul*128;
  const u16* kk = Kp  + (size_t)uh*q_hi_stride + ul*128;
  const u16* vt = VTp + (size_t)uh*vt_hi_stride + (size_t)(ul*128)*vt_ld;
  int lane = threadIdx.x, lr = lane & 15, lk = lane >> 4;
  int r0 = blockIdx.x*16;
  int qr = min(r0 + lr, M-1);
  s16x8 qf[4];
#pragma unroll
  for (int kd=0; kd<4; ++kd) qf[kd] = ld8(q + (size_t)qr*qld + kd*32 + lk*8);
  f32x4 oacc[8];
#pragma unroll
  for (int i=0;i<8;i++) oacc[i] = (f32x4){0,0,0,0};
  float mr[4] = {-1e30f,-1e30f,-1e30f,-1e30f};
  float ls[4] = {0,0,0,0};
  __shared__ u16 plsm[16*80];
  int t0 = (tiles_total * c) / nchunks;
  int t1 = (tiles_total * (c+1)) / nchunks;
  for (int kt=t0; kt<t1; ++kt){
    int kb = kt*64;
    s16x8 kf[16];
#pragma unroll
    for (int n=0;n<4;n++){
      int kc = min(kb + n*16 + lr, Nk-1);
      const u16* kr = kk + (size_t)kc*qld + lk*8;
#pragma unroll
      for (int kd=0; kd<4; ++kd) kf[n*4+kd] = ld8(kr + kd*32);
    }
    f32x4 s[4];
#pragma unroll
    for (int n=0;n<4;n++) s[n] = (f32x4){0,0,0,0};
#pragma unroll
    for (int n=0;n<4;n++)
#pragma unroll
      for (int kd=0; kd<4; ++kd)
        MFMA(s[n], qf[kd], kf[n*4+kd]);
    // scale + key mask
#pragma unroll
    for (int n=0;n<4;n++){
      bool valid = (kb + n*16 + lr) < Nk;
#pragma unroll
      for (int r=0;r<4;r++){
        float v2 = s[n][r]*scale;
        s[n][r] = valid ? v2 : -1e30f;
      }
    }
    float mx[4];
#pragma unroll
    for (int r=0;r<4;r++) mx[r] = fmaxf(fmaxf(s[0][r],s[1][r]), fmaxf(s[2][r],s[3][r]));
#pragma unroll
    for (int off=1; off<16; off<<=1){
#pragma unroll
      for (int r=0;r<4;r++) mx[r] = fmaxf(mx[r], __shfl_xor(mx[r], off, 64));
    }
    float al[4], rs[4];
#pragma unroll
    for (int r=0;r<4;r++){
      float mnew = fmaxf(mr[r], mx[r]);
      al[r] = __expf(mr[r]-mnew);
      mr[r] = mnew;
      rs[r] = 0.f;
    }
#pragma unroll
    for (int n=0;n<4;n++){
#pragma unroll
      for (int r=0;r<4;r++){
        float p = __expf(s[n][r]-mr[r]);
        rs[r] += p;
        plsm[(lk*4+r)*80 + n*16 + lr] = f2b(p);
      }
    }
#pragma unroll
    for (int off=1; off<16; off<<=1){
#pragma unroll
      for (int r=0;r<4;r++) rs[r] += __shfl_xor(rs[r], off, 64);
    }
#pragma unroll
    for (int r=0;r<4;r++) ls[r] = ls[r]*al[r] + rs[r];
#pragma unroll
    for (int cf=0; cf<8; cf++){
#pragma unroll
      for (int r=0;r<4;r++) oacc[cf][r] *= al[r];
    }
    __syncthreads();
#pragma unroll
    for (int kd2=0; kd2<2; ++kd2){
      s16x8 pa = *(const s16x8*)(plsm + lr*80 + kd2*32 + lk*8);
#pragma unroll
      for (int cf=0; cf<8; ++cf){
        s16x8 vb = ld8(vt + (size_t)(cf*16+lr)*vt_ld + kb + kd2*32 + lk*8);
        MFMA(oacc[cf], pa, vb);
      }
    }
    __syncthreads();
  }
  size_t pbase = ((size_t)u*nchunks + c)*M;
#pragma unroll
  for (int cf=0; cf<8; ++cf){
#pragma unroll
    for (int r=0;r<4;r++){
      int row = r0 + lk*4 + r;
      if (row < M) po[(pbase + row)*128 + cf*16 + lr] = oacc[cf][r];
    }
  }
  if (lr == 0){
#pragma unroll
    for (int r=0;r<4;r++){
      int row = r0 + lk*4 + r;
      if (row < M){ pm[pbase + row] = mr[r]; pl[pbase + row] = ls[r]; }
    }
  }
}

// ---------------- flash combine: merge K-chunks, normalize ------------------
__global__ __launch_bounds__(256) void fcomb_kernel(
    const float* __restrict__ po, const float* __restrict__ pm, const float* __restrict__ pl,
    u16* __restrict__ out_bf, float* __restrict__ out_f,
    int rows, int nunits, int nchunks, long o_hi_stride)
{
  int w = threadIdx.x >> 6, lane = threadIdx.x & 63;
  int gid = blockIdx.x*4 + w;
  if (gid >= nunits*rows) return;
  int u = gid / rows, row = gid - u*rows;
  size_t pb = (size_t)u*nchunks*rows + row;
  float m = -1e30f;
  for (int c=0;c<nchunks;c++) m = fmaxf(m, pm[pb + (size_t)c*rows]);
  float L = 0.f, o0 = 0.f, o1 = 0.f;
  for (int c=0;c<nchunks;c++){
    float wgt = __expf(pm[pb + (size_t)c*rows] - m);
    L += wgt * pl[pb + (size_t)c*rows];
    const float* op = po + (pb + (size_t)c*rows)*128;
    o0 += wgt * op[lane*2];
    o1 += wgt * op[lane*2+1];
  }
  float inv = 1.f/L;
  int uh = u>>2, ul = u&3;
  size_t idx = (size_t)uh*o_hi_stride + (size_t)row*512 + ul*128 + lane*2;
  if (out_bf){ out_bf[idx] = f2b(o0*inv); out_bf[idx+1] = f2b(o1*inv); }
  else       { out_f[idx]  = o0*inv;      out_f[idx+1]  = o1*inv; }
}

// ---------------- LayerNorm: one wave per 512-wide row ----------------------
__global__ __launch_bounds__(256) void ln_kernel(
    const u16* __restrict__ inb, const float* __restrict__ inf,
    const u16* __restrict__ gw, const u16* __restrict__ bw,
    u16* __restrict__ out, int rows)
{
  int w = threadIdx.x >> 6, lane = threadIdx.x & 63;
  int row = blockIdx.x*4 + w;
  if (row >= rows) return;
  float x[8];
  if (inb){
    s16x8 v = ld8(inb + (size_t)row*512 + lane*8);
#pragma unroll
    for (int j=0;j<8;j++) x[j] = b2f((u16)v[j]);
  } else {
    const float* p = inf + (size_t)row*512 + lane*8;
#pragma unroll
    for (int j=0;j<8;j++) x[j] = p[j];
  }
  float s = 0.f;
#pragma unroll
  for (int j=0;j<8;j++) s += x[j];
#pragma unroll
  for (int off=1; off<64; off<<=1) s += __shfl_xor(s, off, 64);
  float mean = s*(1.f/512.f);
  float vs = 0.f;
#pragma unroll
  for (int j=0;j<8;j++){ float d = x[j]-mean; vs += d*d; }
#pragma unroll
  for (int off=1; off<64; off<<=1) vs += __shfl_xor(vs, off, 64);
  float rstd = 1.f/sqrtf(vs*(1.f/512.f) + 1e-5f);
#pragma unroll
  for (int j=0;j<8;j++){
    int c = lane*8+j;
    float y = (x[j]-mean)*rstd*b2f(gw[c]) + b2f(bw[c]);
    out[(size_t)row*512 + c] = f2b(y);
  }
}

// ---------------- quadrant gather: xg[(g,l)] = x[n(g,l)] --------------------
__global__ __launch_bounds__(256) void gather_xg_kernel(const u16* __restrict__ x,
                                                        u16* __restrict__ xg)
{
  int w = threadIdx.x >> 6, lane = threadIdx.x & 63;
  int gl = blockIdx.x*4 + w;
  int g = gl/405, l = gl - g*405;
  int a = g >> 1, b = g & 1, hh = l/27, ww = l - hh*27;
  int n = a*810 + hh*54 + b*27 + ww;
  *(s16x8*)(xg + (size_t)gl*512 + lane*8) = *(const s16x8*)(x + (size_t)n*512 + lane*8);
}

// ---------------- xut = xa0 + mean_g ot[g][row%405] -------------------------
__global__ __launch_bounds__(256) void combine_kernel(const float* __restrict__ xa0,
                                                      const float* __restrict__ ot,
                                                      float* __restrict__ xut)
{
  int w = threadIdx.x >> 6, lane = threadIdx.x & 63;
  int row = blockIdx.x*4 + w;
  int l = row % 405;
  int c = lane*8;
  const float* pa = xa0 + (size_t)row*512 + c;
  float acc[8];
#pragma unroll
  for (int j=0;j<8;j++) acc[j] = pa[j];
#pragma unroll
  for (int g2=0; g2<4; ++g2){
    const float* po = ot + ((size_t)(g2*405+l))*512 + c;
#pragma unroll
    for (int j=0;j<8;j++) acc[j] += 0.25f*po[j];
  }
  float* pw = xut + (size_t)row*512 + c;
#pragma unroll
  for (int j=0;j<8;j++) pw[j] = acc[j];
}

// ---------------- mem_fin[0] = x verbatim (dtype-branched) ------------------
__global__ __launch_bounds__(256) void copy_out_kernel(
    const u16* __restrict__ s16, const float* __restrict__ s32,
    const int* __restrict__ flag, u16* __restrict__ dbf, float* __restrict__ df, int n8)
{
  int i = blockIdx.x*256 + threadIdx.x;
  if (i >= n8) return;
  if (*flag){
    ((f32x4*)df)[i*2]   = ((const f32x4*)s32)[i*2];
    ((f32x4*)df)[i*2+1] = ((const f32x4*)s32)[i*2+1];
  } else {
    ((s16x8*)dbf)[i] = ((const s16x8*)s16)[i];
  }
}

// ---------------------------------------------------------------------------
extern "C" void kernel_launch(void* const* d_in, const int* in_sizes, int n_in,
                              void* d_out, int out_size, void* d_ws, size_t ws_size,
                              hipStream_t stream)
{
  u16* outp16 = (u16*)d_out;
  float* outp32 = (float*)d_out;

  char* wsb = (char*)d_ws;
  size_t off = 0;
  auto alloc = [&](size_t bytes)->void*{
    void* p = wsb + off; off += (bytes + 255) & ~(size_t)255; return p; };

  int* flagp = (int*)alloc(256);

  static const int din_idx[23] = {0, 2,3, 4,5, 6,7, 8,9, 10,11, 12,13,
                                  14,15, 16,17, 18,19, 20,21, 22,23};
  static const int din_n[23]   = {829440, 512,512, 262144,512, 262144,512,
                                  262144,512, 262144,512, 512,512,
                                  1048576,2048, 1048576,512, 512,512,
                                  1048576,2048, 1048576,512};
  NormArgs na;
  u16* cptr[23];
  int total = 0;
  for (int i=0;i<23;i++){ na.src[i] = d_in[din_idx[i]]; na.cumblk[i] = total/512; total += din_n[i]; }
  na.cumblk[23] = total/512;
  u16* canon = (u16*)alloc((size_t)total*2);
  { int c = 0; for (int i=0;i<23;i++){ cptr[i] = canon + c; c += din_n[i]; } }
  const u16 *cx=cptr[0], *cg1=cptr[1], *cb1=cptr[2],
            *cwq=cptr[3], *cbq=cptr[4], *cwk=cptr[5], *cbk=cptr[6],
            *cwv=cptr[7], *cbv=cptr[8], *cwo=cptr[9], *cbo=cptr[10],
            *cg2=cptr[11], *cb2=cptr[12], *cw1s=cptr[13], *cfb1s=cptr[14],
            *cw2s=cptr[15], *cfb2s=cptr[16], *ctg2=cptr[17], *ctb2=cptr[18],
            *cw1t=cptr[19], *cfb1t=cptr[20], *cw2t=cptr[21], *cfb2t=cptr[22];

  u16* wqkvT = (u16*)alloc((size_t)1536*512*2);
  u16* woT  = (u16*)alloc(512*512*2);
  u16* w1sT = (u16*)alloc(2048*512*2);
  u16* w2sT = (u16*)alloc((size_t)512*2048*2);
  u16* w1tT = (u16*)alloc(2048*512*2);
  u16* w2tT = (u16*)alloc((size_t)512*2048*2);
  u16* xn   = (u16*)alloc(1620*512*2);
  u16* qkv  = (u16*)alloc((size_t)1620*1536*2);
  u16* vT   = (u16*)alloc((size_t)512*1664*2);
  u16* attn = (u16*)alloc(1620*512*2);
  float* xu = (float*)alloc((size_t)1620*512*4);
  u16* yb   = (u16*)alloc(1620*512*2);
  u16* hh   = (u16*)alloc((size_t)1620*2048*2);
  float* xa0= (float*)alloc((size_t)1620*512*4);
  u16* xg   = (u16*)alloc(1620*512*2);
  u16* xgT  = (u16*)alloc((size_t)4*512*448*2);
  float* ot = (float*)alloc((size_t)4*405*512*4);
  float* xut= (float*)alloc((size_t)1620*512*4);
  u16* yt   = (u16*)alloc(1620*512*2);
  u16* ht   = (u16*)alloc((size_t)1620*2048*2);
  // flash partials (spatial 4u*8c*1620r*128) — also reused as split-K GEMM partials
  float* po = (float*)alloc((size_t)4*8*1620*128*4);
  float* pm = (float*)alloc((size_t)4*8*1620*4);
  float* pl = (float*)alloc((size_t)4*8*1620*4);

  const float scale = 0.08838834764831843f;   // 1/sqrt(128)
  dim3 tb(32,8);

  detect_kernel<<<dim3(1), dim3(64), 0, stream>>>((const u16*)d_in[0], flagp);
  norm_kernel<<<dim3(total/512), dim3(64), 0, stream>>>(na, flagp, canon);

  // batched weight transposes: wq/wk/wv -> wqkvT segments, wo, w1s, w2s, w1t, w2t
  {
    TJobs J;
    const u16* srcs[8] = {cwq, cwk, cwv, cwo, cw1s, cw2s, cw1t, cw2t};
    u16* dsts[8] = {wqkvT, wqkvT + (size_t)512*512, wqkvT + (size_t)1024*512,
                    woT, w1sT, w2sT, w1tT, w2tT};
    int Rs[8]   = {512,512,512,512, 512,2048, 512,2048};
    int Cs[8]   = {512,512,512,512, 2048,512, 2048,512};
    int t2 = 0;
    J.cum[0] = 0;
    for (int i=0;i<8;i++){
      J.src[i]=srcs[i]; J.dst[i]=dsts[i]; J.R[i]=Rs[i]; J.C32[i]=Cs[i]/32;
      J.srcld[i]=Cs[i]; J.dstld[i]=Rs[i];
      t2 += ((Rs[i]+31)/32)*(Cs[i]/32);
      J.cum[i+1]=t2;
    }
    trans_kernel<<<dim3(t2), tb, 0, stream>>>(J);
  }

  // spatial block (only t=0 of the concat survives)
  ln_kernel<<<dim3(405), dim3(256), 0, stream>>>(cx, nullptr, cg1, cb1, xn, 1620);
  // fused QKV: N=1536
  gemm_kernel<<<dim3(24,26), dim3(512), 0, stream>>>(xn, wqkvT, cbq, cbk, cbv,
      1620,1536,512, nullptr,nullptr, qkv, nullptr, nullptr,nullptr,nullptr, 0);
  // vT from qkv V-columns
  {
    TJobs J;
    J.src[0]=qkv+1024; J.dst[0]=vT; J.R[0]=1620; J.C32[0]=512/32;
    J.srcld[0]=1536; J.dstld[0]=1664;
    int t2 = ((1620+31)/32)*(512/32);
    J.cum[0]=0; for (int i=1;i<9;i++) J.cum[i]=t2;
    trans_kernel<<<dim3(t2), tb, 0, stream>>>(J);
  }
  // spatial flash: 102 q-tiles x 4 heads x 8 key-chunks
  flashp_kernel<<<dim3(102,4,8), dim3(64), 0, stream>>>(qkv, qkv+512, vT, po, pm, pl,
      1620, 1620, 1536, 26, 8, 0L, 0L, 1664, scale);
  fcomb_kernel<<<dim3(1620), dim3(256), 0, stream>>>(po, pm, pl, attn, nullptr,
      1620, 4, 8, 0L);
  // O-proj: split-K=2
  gemm_splitk_kernel<<<dim3(8,26,2), dim3(512), 0, stream>>>(attn, woT, 1620,512,512,2, po);
  gemm_comb_kernel<<<dim3(405), dim3(256), 0, stream>>>(po, 2, cbo, 1620,512, 0,
      cx, nullptr, nullptr, xu, nullptr,nullptr,nullptr);
  ln_kernel<<<dim3(405), dim3(256), 0, stream>>>(nullptr, xu, cg2, cb2, yb, 1620);
  gemm_kernel<<<dim3(32,26), dim3(512), 0, stream>>>(yb, w1sT, cfb1s, nullptr,nullptr,
      1620,2048,512, nullptr,nullptr, hh, nullptr, nullptr,nullptr,nullptr, 1);
  // FFN2 spatial: split-K=4; epilogue writes xa0 + mem_fin[1]
  gemm_splitk_kernel<<<dim3(8,26,4), dim3(512), 0, stream>>>(hh, w2sT, 1620,512,2048,4, po);
  gemm_comb_kernel<<<dim3(405), dim3(256), 0, stream>>>(po, 4, cfb2s, 1620,512, 0,
      nullptr, xu, nullptr, xa0, flagp, outp16 + 1658880, outp32 + 1658880);

  // temporal block (attention input is the ORIGINAL x, grouped by quadrant)
  gather_xg_kernel<<<dim3(405), dim3(256), 0, stream>>>(cx, xg);
  {
    TJobs J;
    int per = ((405+31)/32)*(512/32);
    for (int g=0; g<4; ++g){
      J.src[g]=xg + (size_t)g*405*512; J.dst[g]=xgT + (size_t)g*512*448;
      J.R[g]=405; J.C32[g]=512/32; J.srcld[g]=512; J.dstld[g]=448;
    }
    J.cum[0]=0;
    for (int i=1;i<9;i++) J.cum[i] = (i<=4) ? per*i : per*4;
    trans_kernel<<<dim3(per*4), tb, 0, stream>>>(J);
  }
  // temporal flash: 26 q-tiles x 16 (g,h) units x 4 key-chunks
  flashp_kernel<<<dim3(26,16,4), dim3(64), 0, stream>>>(xg, xg, xgT, po, pm, pl,
      405, 405, 512, 7, 4, (long)(405*512), (long)(512*448), 448, scale);
  fcomb_kernel<<<dim3(1620), dim3(256), 0, stream>>>(po, pm, pl, nullptr, ot,
      405, 16, 4, (long)(405*512));
  combine_kernel<<<dim3(405), dim3(256), 0, stream>>>(xa0, ot, xut);
  ln_kernel<<<dim3(405), dim3(256), 0, stream>>>(nullptr, xut, ctg2, ctb2, yt, 1620);
  gemm_kernel<<<dim3(32,26), dim3(512), 0, stream>>>(yt, w1tT, cfb1t, nullptr,nullptr,
      1620,2048,512, nullptr,nullptr, ht, nullptr, nullptr,nullptr,nullptr, 1);
  gemm_splitk_kernel<<<dim3(8,26,4), dim3(512), 0, stream>>>(ht, w2tT, 1620,512,2048,4, po);
  gemm_comb_kernel<<<dim3(405), dim3(256), 0, stream>>>(po, 4, cfb2t, 1620,512, 0,
      nullptr, xut, nullptr, nullptr, flagp, outp16, outp32);

  // mem_fin[0] = x verbatim
  copy_out_kernel<<<dim3(405), dim3(256), 0, stream>>>((const u16*)d_in[0],
      (const float*)d_in[0], flagp, outp16 + 829440, outp32 + 829440, 103680);
}

// Round 8
// 469.875 us; speedup vs baseline: 1.2636x; 1.0644x over previous
//
#include <hip/hip_runtime.h>
#include <stdint.h>

typedef unsigned short u16;
typedef float f32x4 __attribute__((ext_vector_type(4)));
typedef short s16x8 __attribute__((ext_vector_type(8)));

#define DEV __device__ __forceinline__

DEV float b2f(u16 u){ union{unsigned i; float f;} v; v.i = ((unsigned)u)<<16; return v.f; }
DEV u16 f2b(float f){ union{float f; unsigned i;} v; v.f=f; unsigned u=v.i;
                      return (u16)((u + 0x7FFFu + ((u>>16)&1u))>>16); }
DEV s16x8 ld8(const u16* p){ return *(const s16x8*)p; }

#define MFMA(d,a,b) d = __builtin_amdgcn_mfma_f32_16x16x32_bf16(a, b, d, 0, 0, 0)

// ---------------- dtype detection: f32 misread as bf16 has wild exponents ---
__global__ __launch_bounds__(64) void detect_kernel(const u16* __restrict__ x, int* flag){
  int lane = threadIdx.x;
  int cnt = 0;
  for (int i=0;i<32;i++){
    u16 v = x[lane*32+i];
    int e = (v >> 7) & 0xFF;
    if (e >= 0xE0) cnt++;           // |val| >= 2^97: impossible for N(0,1) bf16 data
  }
  for (int off=1; off<64; off<<=1) cnt += __shfl_xor(cnt, off, 64);
  if (lane==0) *flag = (cnt >= 16) ? 1 : 0;   // 1 = device buffers are f32
}

// ---------------- canonicalize all input tensors to contiguous bf16 ---------
struct NormArgs { const void* src[23]; int cumblk[24]; };

__global__ __launch_bounds__(64) void norm_kernel(NormArgs a, const int* __restrict__ flag,
                                                  u16* __restrict__ canon){
  int b = blockIdx.x, lane = threadIdx.x;
  int t = 0;
  while (t < 22 && b >= a.cumblk[t+1]) t++;
  int off = (b - a.cumblk[t])*512 + lane*8;
  size_t g = (size_t)b*512 + lane*8;
  if (*flag){
    const float* s = (const float*)a.src[t] + off;
    s16x8 o;
#pragma unroll
    for (int j=0;j<8;j++) o[j] = (short)f2b(s[j]);
    *(s16x8*)(canon+g) = o;
  } else {
    *(s16x8*)(canon+g) = *(const s16x8*)((const u16*)a.src[t] + off);
  }
}

// ---------------- batched tiled transpose (job table) -----------------------
// dst[c*dstld + r] = src[r*srcld + c]; rows tiled to cover dstld (0-fill pad).
struct TJobs {
  const u16* src[8]; u16* dst[8];
  int R[8], C32[8], srcld[8], dstld[8];
  int cum[9];
};
__global__ void trans_kernel(TJobs J){
  int b = blockIdx.x;
  int t = 0;
  while (b >= J.cum[t+1]) t++;
  int idx = b - J.cum[t];
  int tr = idx / J.C32[t], tc = idx - tr*J.C32[t];
  int r0 = tr*32, c0 = tc*32;
  const u16* src = J.src[t];
  u16* dst = J.dst[t];
  int R = J.R[t], srcld = J.srcld[t], dstld = J.dstld[t];
  __shared__ u16 tile[32][33];
  int tx = threadIdx.x, ty = threadIdx.y;   // (32,8)
#pragma unroll
  for (int i=0;i<4;i++){
    int r = r0 + ty + i*8, c = c0 + tx;
    u16 v = 0;
    if (r < R) v = src[(size_t)r*srcld + c];
    tile[ty+i*8][tx] = v;
  }
  __syncthreads();
#pragma unroll
  for (int i=0;i<4;i++){
    int c = c0 + ty + i*8, r = r0 + tx;
    if (r < dstld) dst[(size_t)c*dstld + r] = tile[tx][ty+i*8];
  }
}

// ---------------- MFMA GEMM: C = A(MxK) @ BT(NxK)^T + bias ------------------
// 8 waves / block, 64x64 tile, wave = 16 rows x 32 cols, direct global frags.
// bias2/bias3: QKV mode (bias per 512-col segment).
__global__ __launch_bounds__(512) void gemm_kernel(
    const u16* __restrict__ A, const u16* __restrict__ BT,
    const u16* __restrict__ bias, const u16* __restrict__ bias2, const u16* __restrict__ bias3,
    int M, int N, int K,
    const u16* __restrict__ resid_bf, const float* __restrict__ resid_f,
    u16* __restrict__ out_bf, float* __restrict__ out_f,
    const int* __restrict__ flagp, u16* __restrict__ dev_bf, float* __restrict__ dev_f,
    int relu)
{
  int tid = threadIdx.x, lane = tid & 63, wid = tid >> 6;
  int wm = wid & 3, wn = wid >> 2;
  int lr = lane & 15, lk = lane >> 4;
  int rowBase = blockIdx.y*64 + wm*16;
  int colBase = blockIdx.x*64 + wn*32;
  int ar  = min(rowBase + lr, M-1);
  int bc0 = colBase + lr, bc1 = colBase + 16 + lr;   // N is a multiple of 64
  const u16* pa  = A  + (size_t)ar*K  + lk*8;
  const u16* pb0 = BT + (size_t)bc0*K + lk*8;
  const u16* pb1 = BT + (size_t)bc1*K + lk*8;
  f32x4 acc0={0,0,0,0}, acc1={0,0,0,0};
#pragma unroll 8
  for (int k0 = 0; k0 < K; k0 += 32){
    s16x8 a  = ld8(pa+k0);
    s16x8 b0 = ld8(pb0+k0), b1 = ld8(pb1+k0);
    MFMA(acc0, a, b0);
    MFMA(acc1, a, b1);
  }
  f32x4 accs[2] = {acc0, acc1};
  int isf32 = flagp ? *flagp : 0;
#pragma unroll
  for (int n=0;n<2;n++){
    int col = colBase + n*16 + lr;
    float bv = 0.f;
    if (bias){
      if (bias2){
        const u16* bp = (col < 512) ? bias : ((col < 1024) ? bias2 : bias3);
        bv = b2f(bp[col & 511]);
      } else bv = b2f(bias[col]);
    }
#pragma unroll
    for (int r=0;r<4;r++){
      int row = rowBase + lk*4 + r;
      if (row < M){
        float v = accs[n][r] + bv;
        if (relu) v = fmaxf(v, 0.f);
        size_t idx = (size_t)row*N + col;
        if (resid_bf) v += b2f(resid_bf[idx]);
        if (resid_f)  v += resid_f[idx];
        if (out_f)  out_f[idx]  = v;
        if (out_bf) out_bf[idx] = f2b(v);
        if (flagp){ if (isf32) dev_f[idx] = v; else dev_bf[idx] = f2b(v); }
      }
    }
  }
}

// ---------------- split-K GEMM partial: pout[z][M][N] (f32, no epilogue) ----
__global__ __launch_bounds__(512) void gemm_splitk_kernel(
    const u16* __restrict__ A, const u16* __restrict__ BT,
    int M, int N, int K, int KS, float* __restrict__ pout)
{
  int tid = threadIdx.x, lane = tid & 63, wid = tid >> 6;
  int wm = wid & 3, wn = wid >> 2;
  int lr = lane & 15, lk = lane >> 4;
  int z = blockIdx.z;
  int kA = (K*z)/KS, kB = (K*(z+1))/KS;
  int rowBase = blockIdx.y*64 + wm*16;
  int colBase = blockIdx.x*64 + wn*32;
  int ar  = min(rowBase + lr, M-1);
  int bc0 = colBase + lr, bc1 = colBase + 16 + lr;
  const u16* pa  = A  + (size_t)ar*K  + lk*8;
  const u16* pb0 = BT + (size_t)bc0*K + lk*8;
  const u16* pb1 = BT + (size_t)bc1*K + lk*8;
  f32x4 acc0={0,0,0,0}, acc1={0,0,0,0};
#pragma unroll 8
  for (int k0 = kA; k0 < kB; k0 += 32){
    s16x8 a  = ld8(pa+k0);
    s16x8 b0 = ld8(pb0+k0), b1 = ld8(pb1+k0);
    MFMA(acc0, a, b0);
    MFMA(acc1, a, b1);
  }
  f32x4 accs[2] = {acc0, acc1};
  float* pz = pout + (size_t)z*M*N;
#pragma unroll
  for (int n=0;n<2;n++){
    int col = colBase + n*16 + lr;
#pragma unroll
    for (int r=0;r<4;r++){
      int row = rowBase + lk*4 + r;
      if (row < M) pz[(size_t)row*N + col] = accs[n][r];
    }
  }
}

// ---------------- split-K combine + epilogue (N=512) ------------------------
__global__ __launch_bounds__(256) void gemm_comb_kernel(
    const float* __restrict__ pout, int KS, const u16* __restrict__ bias,
    int M, int N, int relu,
    const u16* __restrict__ resid_bf, const float* __restrict__ resid_f,
    u16* __restrict__ out_bf, float* __restrict__ out_f,
    const int* __restrict__ flagp, u16* __restrict__ dev_bf, float* __restrict__ dev_f)
{
  int w = threadIdx.x >> 6, lane = threadIdx.x & 63;
  int row = blockIdx.x*4 + w;
  if (row >= M) return;
  int c0 = lane*8;
  float acc[8];
  const float* p0 = pout + (size_t)row*N + c0;
#pragma unroll
  for (int j=0;j<8;j++) acc[j] = p0[j];
  for (int z=1; z<KS; ++z){
    const float* pz = pout + ((size_t)z*M + row)*N + c0;
#pragma unroll
    for (int j=0;j<8;j++) acc[j] += pz[j];
  }
  int isf32 = flagp ? *flagp : 0;
#pragma unroll
  for (int j=0;j<8;j++){
    int col = c0 + j;
    float v = acc[j] + (bias ? b2f(bias[col]) : 0.f);
    if (relu) v = fmaxf(v, 0.f);
    size_t idx = (size_t)row*N + col;
    if (resid_bf) v += b2f(resid_bf[idx]);
    if (resid_f)  v += resid_f[idx];
    if (out_f)  out_f[idx]  = v;
    if (out_bf) out_bf[idx] = f2b(v);
    if (flagp){ if (isf32) dev_f[idx] = v; else dev_bf[idx] = f2b(v); }
  }
}

// ---------------- flash partial, 4 waves/block, LDS-staged K/V tiles --------
// Block: 64 q-rows (wave w owns 16), tile = 64 keys. K/Vt staged coalesced into
// swizzled LDS (elem ^= (row&7)<<3, write/read paired). Partials per key-chunk.
__global__ __launch_bounds__(256) void flash4_kernel(
    const u16* __restrict__ Qp, const u16* __restrict__ Kp, const u16* __restrict__ VTp,
    float* __restrict__ po, float* __restrict__ pm, float* __restrict__ pl,
    int M, int Nk, int qld, int tiles_total, int nchunks,
    long q_hi_stride, long vt_hi_stride, int vt_ld, float scale)
{
  int u = blockIdx.y, c = blockIdx.z;
  int uh = u >> 2, ul = u & 3;
  const u16* q  = Qp  + (size_t)uh*q_hi_stride + ul*128;
  const u16* kk = Kp  + (size_t)uh*q_hi_stride + ul*128;
  const u16* vt = VTp + (size_t)uh*vt_hi_stride + (size_t)(ul*128)*vt_ld;
  int tid = threadIdx.x, lane = tid & 63, w = tid >> 6;
  int lr = lane & 15, lk = lane >> 4;
  int r0 = blockIdx.x*64 + w*16;
  int qr = min(r0 + lr, M-1);

  __shared__ u16 Klds[64*128];      // [key][128d], swizzled
  __shared__ u16 Vlds[128*64];      // [d][64key], swizzled
  __shared__ u16 plsm[4][16*80];    // per-wave P transpose

  s16x8 qf[4];
#pragma unroll
  for (int kd=0; kd<4; ++kd) qf[kd] = ld8(q + (size_t)qr*qld + kd*32 + lk*8);
  f32x4 oacc[8];
#pragma unroll
  for (int i=0;i<8;i++) oacc[i] = (f32x4){0,0,0,0};
  float mr[4] = {-1e30f,-1e30f,-1e30f,-1e30f};
  float ls[4] = {0,0,0,0};

  int t0 = (tiles_total * c) / nchunks;
  int t1 = (tiles_total * (c+1)) / nchunks;
  for (int kt=t0; kt<t1; ++kt){
    int kb = kt*64;
    // ---- coalesced staging: 64x128 K tile + 128x64 Vt tile, both swizzled
#pragma unroll
    for (int it=0; it<4; ++it){
      int ch = it*256 + tid;
      int key = ch >> 4, seg = ch & 15;
      int kg = min(kb + key, Nk-1);
      s16x8 kvv = ld8(kk + (size_t)kg*qld + seg*8);
      int dd = ch >> 3, sg = ch & 7;
      s16x8 vvv = ld8(vt + (size_t)dd*vt_ld + kb + sg*8);
      *(s16x8*)(Klds + key*128 + ((seg*8) ^ ((key&7)<<3))) = kvv;
      *(s16x8*)(Vlds + dd*64  + ((sg*8)  ^ ((dd&7)<<3)))  = vvv;
    }
    __syncthreads();
    // ---- QK^T from LDS
    f32x4 s[4];
#pragma unroll
    for (int n=0;n<4;n++) s[n] = (f32x4){0,0,0,0};
#pragma unroll
    for (int n=0;n<4;n++){
      int key = n*16 + lr;
#pragma unroll
      for (int kd=0; kd<4; ++kd){
        s16x8 kf = *(const s16x8*)(Klds + key*128 + ((kd*32 + lk*8) ^ ((key&7)<<3)));
        MFMA(s[n], qf[kd], kf);
      }
    }
    // scale + key mask
#pragma unroll
    for (int n=0;n<4;n++){
      bool valid = (kb + n*16 + lr) < Nk;
#pragma unroll
      for (int r=0;r<4;r++){
        float v2 = s[n][r]*scale;
        s[n][r] = valid ? v2 : -1e30f;
      }
    }
    float mx[4];
#pragma unroll
    for (int r=0;r<4;r++) mx[r] = fmaxf(fmaxf(s[0][r],s[1][r]), fmaxf(s[2][r],s[3][r]));
#pragma unroll
    for (int off=1; off<16; off<<=1){
#pragma unroll
      for (int r=0;r<4;r++) mx[r] = fmaxf(mx[r], __shfl_xor(mx[r], off, 64));
    }
    float al[4], rs[4];
#pragma unroll
    for (int r=0;r<4;r++){
      float mnew = fmaxf(mr[r], mx[r]);
      al[r] = __expf(mr[r]-mnew);
      mr[r] = mnew;
      rs[r] = 0.f;
    }
#pragma unroll
    for (int n=0;n<4;n++){
#pragma unroll
      for (int r=0;r<4;r++){
        float p = __expf(s[n][r]-mr[r]);
        rs[r] += p;
        plsm[w][(lk*4+r)*80 + n*16 + lr] = f2b(p);
      }
    }
#pragma unroll
    for (int off=1; off<16; off<<=1){
#pragma unroll
      for (int r=0;r<4;r++) rs[r] += __shfl_xor(rs[r], off, 64);
    }
#pragma unroll
    for (int r=0;r<4;r++) ls[r] = ls[r]*al[r] + rs[r];
#pragma unroll
    for (int cf=0; cf<8; cf++){
#pragma unroll
      for (int r=0;r<4;r++) oacc[cf][r] *= al[r];
    }
    __syncthreads();
    // ---- PV from LDS
#pragma unroll
    for (int kd2=0; kd2<2; ++kd2){
      s16x8 pa = *(const s16x8*)(plsm[w] + lr*80 + kd2*32 + lk*8);
#pragma unroll
      for (int cf=0; cf<8; ++cf){
        int dd = cf*16 + lr;
        s16x8 vb = *(const s16x8*)(Vlds + dd*64 + ((kd2*32 + lk*8) ^ ((dd&7)<<3)));
        MFMA(oacc[cf], pa, vb);
      }
    }
    __syncthreads();   // before next tile's staging overwrites K/V
  }
  size_t pbase = ((size_t)u*nchunks + c)*M;
#pragma unroll
  for (int cf=0; cf<8; ++cf){
#pragma unroll
    for (int r=0;r<4;r++){
      int row = r0 + lk*4 + r;
      if (row < M) po[(pbase + row)*128 + cf*16 + lr] = oacc[cf][r];
    }
  }
  if (lr == 0){
#pragma unroll
    for (int r=0;r<4;r++){
      int row = r0 + lk*4 + r;
      if (row < M){ pm[pbase + row] = mr[r]; pl[pbase + row] = ls[r]; }
    }
  }
}

// ---------------- flash combine: merge K-chunks, normalize ------------------
__global__ __launch_bounds__(256) void fcomb_kernel(
    const float* __restrict__ po, const float* __restrict__ pm, const float* __restrict__ pl,
    u16* __restrict__ out_bf, float* __restrict__ out_f,
    int rows, int nunits, int nchunks, long o_hi_stride)
{
  int w = threadIdx.x >> 6, lane = threadIdx.x & 63;
  int gid = blockIdx.x*4 + w;
  if (gid >= nunits*rows) return;
  int u = gid / rows, row = gid - u*rows;
  size_t pb = (size_t)u*nchunks*rows + row;
  float m = -1e30f;
  for (int c=0;c<nchunks;c++) m = fmaxf(m, pm[pb + (size_t)c*rows]);
  float L = 0.f, o0 = 0.f, o1 = 0.f;
  for (int c=0;c<nchunks;c++){
    float wgt = __expf(pm[pb + (size_t)c*rows] - m);
    L += wgt * pl[pb + (size_t)c*rows];
    const float* op = po + (pb + (size_t)c*rows)*128;
    o0 += wgt * op[lane*2];
    o1 += wgt * op[lane*2+1];
  }
  float inv = 1.f/L;
  int uh = u>>2, ul = u&3;
  size_t idx = (size_t)uh*o_hi_stride + (size_t)row*512 + ul*128 + lane*2;
  if (out_bf){ out_bf[idx] = f2b(o0*inv); out_bf[idx+1] = f2b(o1*inv); }
  else       { out_f[idx]  = o0*inv;      out_f[idx+1]  = o1*inv; }
}

// ---------------- LayerNorm: one wave per 512-wide row ----------------------
__global__ __launch_bounds__(256) void ln_kernel(
    const u16* __restrict__ inb, const float* __restrict__ inf,
    const u16* __restrict__ gw, const u16* __restrict__ bw,
    u16* __restrict__ out, int rows)
{
  int w = threadIdx.x >> 6, lane = threadIdx.x & 63;
  int row = blockIdx.x*4 + w;
  if (row >= rows) return;
  float x[8];
  if (inb){
    s16x8 v = ld8(inb + (size_t)row*512 + lane*8);
#pragma unroll
    for (int j=0;j<8;j++) x[j] = b2f((u16)v[j]);
  } else {
    const float* p = inf + (size_t)row*512 + lane*8;
#pragma unroll
    for (int j=0;j<8;j++) x[j] = p[j];
  }
  float s = 0.f;
#pragma unroll
  for (int j=0;j<8;j++) s += x[j];
#pragma unroll
  for (int off=1; off<64; off<<=1) s += __shfl_xor(s, off, 64);
  float mean = s*(1.f/512.f);
  float vs = 0.f;
#pragma unroll
  for (int j=0;j<8;j++){ float d = x[j]-mean; vs += d*d; }
#pragma unroll
  for (int off=1; off<64; off<<=1) vs += __shfl_xor(vs, off, 64);
  float rstd = 1.f/sqrtf(vs*(1.f/512.f) + 1e-5f);
#pragma unroll
  for (int j=0;j<8;j++){
    int c = lane*8+j;
    float y = (x[j]-mean)*rstd*b2f(gw[c]) + b2f(bw[c]);
    out[(size_t)row*512 + c] = f2b(y);
  }
}

// ---------------- quadrant gather: xg[(g,l)] = x[n(g,l)] --------------------
__global__ __launch_bounds__(256) void gather_xg_kernel(const u16* __restrict__ x,
                                                        u16* __restrict__ xg)
{
  int w = threadIdx.x >> 6, lane = threadIdx.x & 63;
  int gl = blockIdx.x*4 + w;
  int g = gl/405, l = gl - g*405;
  int a = g >> 1, b = g & 1, hh = l/27, ww = l - hh*27;
  int n = a*810 + hh*54 + b*27 + ww;
  *(s16x8*)(xg + (size_t)gl*512 + lane*8) = *(const s16x8*)(x + (size_t)n*512 + lane*8);
}

// ---------------- xut = xa0 + mean_g ot[g][row%405] -------------------------
__global__ __launch_bounds__(256) void combine_kernel(const float* __restrict__ xa0,
                                                      const float* __restrict__ ot,
                                                      float* __restrict__ xut)
{
  int w = threadIdx.x >> 6, lane = threadIdx.x & 63;
  int row = blockIdx.x*4 + w;
  int l = row % 405;
  int c = lane*8;
  const float* pa = xa0 + (size_t)row*512 + c;
  float acc[8];
#pragma unroll
  for (int j=0;j<8;j++) acc[j] = pa[j];
#pragma unroll
  for (int g2=0; g2<4; ++g2){
    const float* po = ot + ((size_t)(g2*405+l))*512 + c;
#pragma unroll
    for (int j=0;j<8;j++) acc[j] += 0.25f*po[j];
  }
  float* pw = xut + (size_t)row*512 + c;
#pragma unroll
  for (int j=0;j<8;j++) pw[j] = acc[j];
}

// ---------------- mem_fin[0] = x verbatim (dtype-branched) ------------------
__global__ __launch_bounds__(256) void copy_out_kernel(
    const u16* __restrict__ s16, const float* __restrict__ s32,
    const int* __restrict__ flag, u16* __restrict__ dbf, float* __restrict__ df, int n8)
{
  int i = blockIdx.x*256 + threadIdx.x;
  if (i >= n8) return;
  if (*flag){
    ((f32x4*)df)[i*2]   = ((const f32x4*)s32)[i*2];
    ((f32x4*)df)[i*2+1] = ((const f32x4*)s32)[i*2+1];
  } else {
    ((s16x8*)dbf)[i] = ((const s16x8*)s16)[i];
  }
}

// ---------------------------------------------------------------------------
extern "C" void kernel_launch(void* const* d_in, const int* in_sizes, int n_in,
                              void* d_out, int out_size, void* d_ws, size_t ws_size,
                              hipStream_t stream)
{
  u16* outp16 = (u16*)d_out;
  float* outp32 = (float*)d_out;

  char* wsb = (char*)d_ws;
  size_t off = 0;
  auto alloc = [&](size_t bytes)->void*{
    void* p = wsb + off; off += (bytes + 255) & ~(size_t)255; return p; };

  int* flagp = (int*)alloc(256);

  static const int din_idx[23] = {0, 2,3, 4,5, 6,7, 8,9, 10,11, 12,13,
                                  14,15, 16,17, 18,19, 20,21, 22,23};
  static const int din_n[23]   = {829440, 512,512, 262144,512, 262144,512,
                                  262144,512, 262144,512, 512,512,
                                  1048576,2048, 1048576,512, 512,512,
                                  1048576,2048, 1048576,512};
  NormArgs na;
  u16* cptr[23];
  int total = 0;
  for (int i=0;i<23;i++){ na.src[i] = d_in[din_idx[i]]; na.cumblk[i] = total/512; total += din_n[i]; }
  na.cumblk[23] = total/512;
  u16* canon = (u16*)alloc((size_t)total*2);
  { int c = 0; for (int i=0;i<23;i++){ cptr[i] = canon + c; c += din_n[i]; } }
  const u16 *cx=cptr[0], *cg1=cptr[1], *cb1=cptr[2],
            *cwq=cptr[3], *cbq=cptr[4], *cwk=cptr[5], *cbk=cptr[6],
            *cwv=cptr[7], *cbv=cptr[8], *cwo=cptr[9], *cbo=cptr[10],
            *cg2=cptr[11], *cb2=cptr[12], *cw1s=cptr[13], *cfb1s=cptr[14],
            *cw2s=cptr[15], *cfb2s=cptr[16], *ctg2=cptr[17], *ctb2=cptr[18],
            *cw1t=cptr[19], *cfb1t=cptr[20], *cw2t=cptr[21], *cfb2t=cptr[22];

  u16* wqkvT = (u16*)alloc((size_t)1536*512*2);
  u16* woT  = (u16*)alloc(512*512*2);
  u16* w1sT = (u16*)alloc(2048*512*2);
  u16* w2sT = (u16*)alloc((size_t)512*2048*2);
  u16* w1tT = (u16*)alloc(2048*512*2);
  u16* w2tT = (u16*)alloc((size_t)512*2048*2);
  u16* xn   = (u16*)alloc(1620*512*2);
  u16* qkv  = (u16*)alloc((size_t)1620*1536*2);
  u16* vT   = (u16*)alloc((size_t)512*1664*2);
  u16* attn = (u16*)alloc(1620*512*2);
  float* xu = (float*)alloc((size_t)1620*512*4);
  u16* yb   = (u16*)alloc(1620*512*2);
  u16* hh   = (u16*)alloc((size_t)1620*2048*2);
  float* xa0= (float*)alloc((size_t)1620*512*4);
  u16* xg   = (u16*)alloc(1620*512*2);
  u16* xgT  = (u16*)alloc((size_t)4*512*448*2);
  float* ot = (float*)alloc((size_t)4*405*512*4);
  float* xut= (float*)alloc((size_t)1620*512*4);
  u16* yt   = (u16*)alloc(1620*512*2);
  u16* ht   = (u16*)alloc((size_t)1620*2048*2);
  // flash partials (spatial 4u*8c*1620r*128) — also reused as split-K GEMM partials
  float* po = (float*)alloc((size_t)4*8*1620*128*4);
  float* pm = (float*)alloc((size_t)4*8*1620*4);
  float* pl = (float*)alloc((size_t)4*8*1620*4);

  const float scale = 0.08838834764831843f;   // 1/sqrt(128)
  dim3 tb(32,8);

  detect_kernel<<<dim3(1), dim3(64), 0, stream>>>((const u16*)d_in[0], flagp);
  norm_kernel<<<dim3(total/512), dim3(64), 0, stream>>>(na, flagp, canon);

  // batched weight transposes
  {
    TJobs J;
    const u16* srcs[8] = {cwq, cwk, cwv, cwo, cw1s, cw2s, cw1t, cw2t};
    u16* dsts[8] = {wqkvT, wqkvT + (size_t)512*512, wqkvT + (size_t)1024*512,
                    woT, w1sT, w2sT, w1tT, w2tT};
    int Rs[8]   = {512,512,512,512, 512,2048, 512,2048};
    int Cs[8]   = {512,512,512,512, 2048,512, 2048,512};
    int t2 = 0;
    J.cum[0] = 0;
    for (int i=0;i<8;i++){
      J.src[i]=srcs[i]; J.dst[i]=dsts[i]; J.R[i]=Rs[i]; J.C32[i]=Cs[i]/32;
      J.srcld[i]=Cs[i]; J.dstld[i]=Rs[i];
      t2 += (Rs[i]/32)*(Cs[i]/32);
      J.cum[i+1]=t2;
    }
    trans_kernel<<<dim3(t2), tb, 0, stream>>>(J);
  }

  // spatial block (only t=0 of the concat survives)
  ln_kernel<<<dim3(405), dim3(256), 0, stream>>>(cx, nullptr, cg1, cb1, xn, 1620);
  gemm_kernel<<<dim3(24,26), dim3(512), 0, stream>>>(xn, wqkvT, cbq, cbk, cbv,
      1620,1536,512, nullptr,nullptr, qkv, nullptr, nullptr,nullptr,nullptr, 0);
  // vT from qkv V-columns: row-tiles cover dstld=1664 (pad rows written as 0)
  {
    TJobs J;
    J.src[0]=qkv+1024; J.dst[0]=vT; J.R[0]=1620; J.C32[0]=512/32;
    J.srcld[0]=1536; J.dstld[0]=1664;
    int t2 = (1664/32)*(512/32);   // 52*16
    J.cum[0]=0; for (int i=1;i<9;i++) J.cum[i]=t2;
    trans_kernel<<<dim3(t2), tb, 0, stream>>>(J);
  }
  // spatial flash: 26 q-tiles x 4 heads x 8 key-chunks, 4 waves/block
  flash4_kernel<<<dim3(26,4,8), dim3(256), 0, stream>>>(qkv, qkv+512, vT, po, pm, pl,
      1620, 1620, 1536, 26, 8, 0L, 0L, 1664, scale);
  fcomb_kernel<<<dim3(1620), dim3(256), 0, stream>>>(po, pm, pl, attn, nullptr,
      1620, 4, 8, 0L);
  // O-proj: split-K=2
  gemm_splitk_kernel<<<dim3(8,26,2), dim3(512), 0, stream>>>(attn, woT, 1620,512,512,2, po);
  gemm_comb_kernel<<<dim3(405), dim3(256), 0, stream>>>(po, 2, cbo, 1620,512, 0,
      cx, nullptr, nullptr, xu, nullptr,nullptr,nullptr);
  ln_kernel<<<dim3(405), dim3(256), 0, stream>>>(nullptr, xu, cg2, cb2, yb, 1620);
  gemm_kernel<<<dim3(32,26), dim3(512), 0, stream>>>(yb, w1sT, cfb1s, nullptr,nullptr,
      1620,2048,512, nullptr,nullptr, hh, nullptr, nullptr,nullptr,nullptr, 1);
  gemm_splitk_kernel<<<dim3(8,26,4), dim3(512), 0, stream>>>(hh, w2sT, 1620,512,2048,4, po);
  gemm_comb_kernel<<<dim3(405), dim3(256), 0, stream>>>(po, 4, cfb2s, 1620,512, 0,
      nullptr, xu, nullptr, xa0, flagp, outp16 + 1658880, outp32 + 1658880);

  // temporal block (attention input is the ORIGINAL x, grouped by quadrant)
  gather_xg_kernel<<<dim3(405), dim3(256), 0, stream>>>(cx, xg);
  {
    TJobs J;
    int per = (448/32)*(512/32);   // 14*16 — cover dstld=448 (pad rows -> 0)
    for (int g=0; g<4; ++g){
      J.src[g]=xg + (size_t)g*405*512; J.dst[g]=xgT + (size_t)g*512*448;
      J.R[g]=405; J.C32[g]=512/32; J.srcld[g]=512; J.dstld[g]=448;
    }
    J.cum[0]=0;
    for (int i=1;i<9;i++) J.cum[i] = (i<=4) ? per*i : per*4;
    trans_kernel<<<dim3(per*4), tb, 0, stream>>>(J);
  }
  // temporal flash: 7 q-tiles x 16 (g,h) units x 7 chunks (1 tile each)
  flash4_kernel<<<dim3(7,16,7), dim3(256), 0, stream>>>(xg, xg, xgT, po, pm, pl,
      405, 405, 512, 7, 7, (long)(405*512), (long)(512*448), 448, scale);
  fcomb_kernel<<<dim3(1620), dim3(256), 0, stream>>>(po, pm, pl, nullptr, ot,
      405, 16, 7, (long)(405*512));
  combine_kernel<<<dim3(405), dim3(256), 0, stream>>>(xa0, ot, xut);
  ln_kernel<<<dim3(405), dim3(256), 0, stream>>>(nullptr, xut, ctg2, ctb2, yt, 1620);
  gemm_kernel<<<dim3(32,26), dim3(512), 0, stream>>>(yt, w1tT, cfb1t, nullptr,nullptr,
      1620,2048,512, nullptr,nullptr, ht, nullptr, nullptr,nullptr,nullptr, 1);
  gemm_splitk_kernel<<<dim3(8,26,4), dim3(512), 0, stream>>>(ht, w2tT, 1620,512,2048,4, po);
  gemm_comb_kernel<<<dim3(405), dim3(256), 0, stream>>>(po, 4, cfb2t, 1620,512, 0,
      nullptr, xut, nullptr, nullptr, flagp, outp16, outp32);

  // mem_fin[0] = x verbatim
  copy_out_kernel<<<dim3(405), dim3(256), 0, stream>>>((const u16*)d_in[0],
      (const float*)d_in[0], flagp, outp16 + 829440, outp32 + 829440, 103680);
}

// Round 9
// 308.254 us; speedup vs baseline: 1.9261x; 1.5243x over previous
//
#include <hip/hip_runtime.h>
#include <stdint.h>

typedef unsigned short u16;
typedef float f32x4 __attribute__((ext_vector_type(4)));
typedef short s16x8 __attribute__((ext_vector_type(8)));

#define DEV __device__ __forceinline__

DEV float b2f(u16 u){ union{unsigned i; float f;} v; v.i = ((unsigned)u)<<16; return v.f; }
DEV u16 f2b(float f){ union{float f; unsigned i;} v; v.f=f; unsigned u=v.i;
                      return (u16)((u + 0x7FFFu + ((u>>16)&1u))>>16); }
DEV s16x8 ld8(const u16* p){ return *(const s16x8*)p; }

#define MFMA(d,a,b) d = __builtin_amdgcn_mfma_f32_16x16x32_bf16(a, b, d, 0, 0, 0)

// async 16B global->LDS (wave-uniform LDS base + lane*16 by construction)
DEV void gload16(const u16* g, u16* l){
  __builtin_amdgcn_global_load_lds((const __attribute__((address_space(1))) void*)g,
                                   (__attribute__((address_space(3))) void*)l, 16, 0, 0);
}

// ---------------- dtype detection: f32 misread as bf16 has wild exponents ---
__global__ __launch_bounds__(64) void detect_kernel(const u16* __restrict__ x, int* flag){
  int lane = threadIdx.x;
  int cnt = 0;
  for (int i=0;i<32;i++){
    u16 v = x[lane*32+i];
    int e = (v >> 7) & 0xFF;
    if (e >= 0xE0) cnt++;           // |val| >= 2^97: impossible for N(0,1) bf16 data
  }
  for (int off=1; off<64; off<<=1) cnt += __shfl_xor(cnt, off, 64);
  if (lane==0) *flag = (cnt >= 16) ? 1 : 0;   // 1 = device buffers are f32
}

// ---------------- canonicalize all input tensors to contiguous bf16 ---------
struct NormArgs { const void* src[23]; int cumblk[24]; };

__global__ __launch_bounds__(64) void norm_kernel(NormArgs a, const int* __restrict__ flag,
                                                  u16* __restrict__ canon){
  int b = blockIdx.x, lane = threadIdx.x;
  int t = 0;
  while (t < 22 && b >= a.cumblk[t+1]) t++;
  int off = (b - a.cumblk[t])*512 + lane*8;
  size_t g = (size_t)b*512 + lane*8;
  if (*flag){
    const float* s = (const float*)a.src[t] + off;
    s16x8 o;
#pragma unroll
    for (int j=0;j<8;j++) o[j] = (short)f2b(s[j]);
    *(s16x8*)(canon+g) = o;
  } else {
    *(s16x8*)(canon+g) = *(const s16x8*)((const u16*)a.src[t] + off);
  }
}

// ---------------- batched tiled transpose (job table) -----------------------
struct TJobs {
  const u16* src[8]; u16* dst[8];
  int R[8], C32[8], srcld[8], dstld[8];
  int cum[9];
};
__global__ void trans_kernel(TJobs J){
  int b = blockIdx.x;
  int t = 0;
  while (b >= J.cum[t+1]) t++;
  int idx = b - J.cum[t];
  int tr = idx / J.C32[t], tc = idx - tr*J.C32[t];
  int r0 = tr*32, c0 = tc*32;
  const u16* src = J.src[t];
  u16* dst = J.dst[t];
  int R = J.R[t], srcld = J.srcld[t], dstld = J.dstld[t];
  __shared__ u16 tile[32][33];
  int tx = threadIdx.x, ty = threadIdx.y;   // (32,8)
#pragma unroll
  for (int i=0;i<4;i++){
    int r = r0 + ty + i*8, c = c0 + tx;
    u16 v = 0;
    if (r < R) v = src[(size_t)r*srcld + c];
    tile[ty+i*8][tx] = v;
  }
  __syncthreads();
#pragma unroll
  for (int i=0;i<4;i++){
    int c = c0 + ty + i*8, r = r0 + tx;
    if (r < dstld) dst[(size_t)c*dstld + r] = tile[tx][ty+i*8];
  }
}

// ---------------- LDS-staged MFMA GEMM: C = A(MxK) @ BT(NxK)^T --------------
// 64x64 tile, BK=64, 4 waves (wave = 32x32 = 2x2 frags), double-buffered LDS
// via global_load_lds w=16. XOR swizzle on SOURCE addr + same XOR on ds_read
// (linear LDS dest — technique #21). One vmcnt(0)+barrier per K-step.
// KS>1: write f32 partial pout[z][M][N] (no epilogue); else full epilogue.
__global__ __launch_bounds__(256) void gemm_s_kernel(
    const u16* __restrict__ A, const u16* __restrict__ BT,
    const u16* __restrict__ bias, const u16* __restrict__ bias2, const u16* __restrict__ bias3,
    int M, int N, int K, int KS, float* __restrict__ pout,
    const u16* __restrict__ resid_bf, const float* __restrict__ resid_f,
    u16* __restrict__ out_bf, float* __restrict__ out_f,
    const int* __restrict__ flagp, u16* __restrict__ dev_bf, float* __restrict__ dev_f,
    int relu)
{
  __shared__ u16 Al[2][64*64];
  __shared__ u16 Bl[2][64*64];
  int tid = threadIdx.x, lane = tid & 63, w = tid >> 6;
  int lr = lane & 15, lk = lane >> 4;
  int wr = w >> 1, wc = w & 1;
  int rowBase = blockIdx.y*64, colBase = blockIdx.x*64;
  int z = blockIdx.z;
  int kStep = K / KS;                 // always a multiple of 64
  int kOff = kStep * z;
  int nk = kStep >> 6;

  f32x4 acc[2][2] = {{{0,0,0,0},{0,0,0,0}},{{0,0,0,0},{0,0,0,0}}};

  // stage K-tile kt into buffer buf (A and B tiles, 4 gload_lds per thread)
  auto STAGE = [&](int buf, int kt){
    int kb = kOff + kt*64;
#pragma unroll
    for (int it=0; it<2; ++it){
      int ch  = it*256 + tid;          // 0..511 chunks of 8 elems
      int row = ch >> 3, seg = ch & 7;
      int sseg = (seg ^ (row & 7)) << 3;     // inverse-swizzled source
      int ar = min(rowBase + row, M-1);
      gload16(A  + (size_t)ar*K + kb + sseg, Al[buf] + ch*8);
      int bc = colBase + row;                // N multiple of 64: no clamp
      gload16(BT + (size_t)bc*K + kb + sseg, Bl[buf] + ch*8);
    }
  };

  STAGE(0, 0);
  asm volatile("s_waitcnt vmcnt(0)" ::: "memory");
  __syncthreads();
  int cur = 0;
  for (int kt=0; kt<nk; ++kt){
    if (kt+1 < nk) STAGE(cur^1, kt+1);
#pragma unroll
    for (int ks=0; ks<2; ++ks){
      s16x8 af[2], bf[2];
#pragma unroll
      for (int m=0;m<2;m++){
        int ar = wr*32 + m*16 + lr;
        af[m] = *(const s16x8*)(Al[cur] + ar*64 + ((((ks<<2)+lk) ^ (ar&7))<<3));
        int bc = wc*32 + m*16 + lr;
        bf[m] = *(const s16x8*)(Bl[cur] + bc*64 + ((((ks<<2)+lk) ^ (bc&7))<<3));
      }
#pragma unroll
      for (int m=0;m<2;m++)
#pragma unroll
        for (int n=0;n<2;n++) MFMA(acc[m][n], af[m], bf[n]);
    }
    asm volatile("s_waitcnt vmcnt(0)" ::: "memory");
    __syncthreads();
    cur ^= 1;
  }

  if (pout){
    float* pz = pout + (size_t)z*M*N;
#pragma unroll
    for (int m=0;m<2;m++)
#pragma unroll
      for (int n=0;n<2;n++){
        int col = colBase + wc*32 + n*16 + lr;
#pragma unroll
        for (int r=0;r<4;r++){
          int row = rowBase + wr*32 + m*16 + lk*4 + r;
          if (row < M) pz[(size_t)row*N + col] = acc[m][n][r];
        }
      }
    return;
  }
  int isf32 = flagp ? *flagp : 0;
#pragma unroll
  for (int m=0;m<2;m++){
#pragma unroll
    for (int n=0;n<2;n++){
      int col = colBase + wc*32 + n*16 + lr;
      float bv = 0.f;
      if (bias){
        if (bias2){
          const u16* bp = (col < 512) ? bias : ((col < 1024) ? bias2 : bias3);
          bv = b2f(bp[col & 511]);
        } else bv = b2f(bias[col]);
      }
#pragma unroll
      for (int r=0;r<4;r++){
        int row = rowBase + wr*32 + m*16 + lk*4 + r;
        if (row < M){
          float v = acc[m][n][r] + bv;
          if (relu) v = fmaxf(v, 0.f);
          size_t idx = (size_t)row*N + col;
          if (resid_bf) v += b2f(resid_bf[idx]);
          if (resid_f)  v += resid_f[idx];
          if (out_f)  out_f[idx]  = v;
          if (out_bf) out_bf[idx] = f2b(v);
          if (flagp){ if (isf32) dev_f[idx] = v; else dev_bf[idx] = f2b(v); }
        }
      }
    }
  }
}

// ---------------- split-K combine + epilogue (N=512) ------------------------
__global__ __launch_bounds__(256) void gemm_comb_kernel(
    const float* __restrict__ pout, int KS, const u16* __restrict__ bias,
    int M, int N, int relu,
    const u16* __restrict__ resid_bf, const float* __restrict__ resid_f,
    u16* __restrict__ out_bf, float* __restrict__ out_f,
    const int* __restrict__ flagp, u16* __restrict__ dev_bf, float* __restrict__ dev_f)
{
  int w = threadIdx.x >> 6, lane = threadIdx.x & 63;
  int row = blockIdx.x*4 + w;
  if (row >= M) return;
  int c0 = lane*8;
  float acc[8];
  const float* p0 = pout + (size_t)row*N + c0;
#pragma unroll
  for (int j=0;j<8;j++) acc[j] = p0[j];
  for (int z=1; z<KS; ++z){
    const float* pz = pout + ((size_t)z*M + row)*N + c0;
#pragma unroll
    for (int j=0;j<8;j++) acc[j] += pz[j];
  }
  int isf32 = flagp ? *flagp : 0;
#pragma unroll
  for (int j=0;j<8;j++){
    int col = c0 + j;
    float v = acc[j] + (bias ? b2f(bias[col]) : 0.f);
    if (relu) v = fmaxf(v, 0.f);
    size_t idx = (size_t)row*N + col;
    if (resid_bf) v += b2f(resid_bf[idx]);
    if (resid_f)  v += resid_f[idx];
    if (out_f)  out_f[idx]  = v;
    if (out_bf) out_bf[idx] = f2b(v);
    if (flagp){ if (isf32) dev_f[idx] = v; else dev_bf[idx] = f2b(v); }
  }
}

// ---------------- flash partial, 4 waves/block, LDS-staged K/V tiles --------
__global__ __launch_bounds__(256) void flash4_kernel(
    const u16* __restrict__ Qp, const u16* __restrict__ Kp, const u16* __restrict__ VTp,
    float* __restrict__ po, float* __restrict__ pm, float* __restrict__ pl,
    int M, int Nk, int qld, int tiles_total, int nchunks,
    long q_hi_stride, long vt_hi_stride, int vt_ld, float scale)
{
  int u = blockIdx.y, c = blockIdx.z;
  int uh = u >> 2, ul = u & 3;
  const u16* q  = Qp  + (size_t)uh*q_hi_stride + ul*128;
  const u16* kk = Kp  + (size_t)uh*q_hi_stride + ul*128;
  const u16* vt = VTp + (size_t)uh*vt_hi_stride + (size_t)(ul*128)*vt_ld;
  int tid = threadIdx.x, lane = tid & 63, w = tid >> 6;
  int lr = lane & 15, lk = lane >> 4;
  int r0 = blockIdx.x*64 + w*16;
  int qr = min(r0 + lr, M-1);

  __shared__ u16 Klds[64*128];
  __shared__ u16 Vlds[128*64];
  __shared__ u16 plsm[4][16*80];

  s16x8 qf[4];
#pragma unroll
  for (int kd=0; kd<4; ++kd) qf[kd] = ld8(q + (size_t)qr*qld + kd*32 + lk*8);
  f32x4 oacc[8];
#pragma unroll
  for (int i=0;i<8;i++) oacc[i] = (f32x4){0,0,0,0};
  float mr[4] = {-1e30f,-1e30f,-1e30f,-1e30f};
  float ls[4] = {0,0,0,0};

  int t0 = (tiles_total * c) / nchunks;
  int t1 = (tiles_total * (c+1)) / nchunks;
  for (int kt=t0; kt<t1; ++kt){
    int kb = kt*64;
#pragma unroll
    for (int it=0; it<4; ++it){
      int ch = it*256 + tid;
      int key = ch >> 4, seg = ch & 15;
      int kg = min(kb + key, Nk-1);
      s16x8 kvv = ld8(kk + (size_t)kg*qld + seg*8);
      int dd = ch >> 3, sg = ch & 7;
      s16x8 vvv = ld8(vt + (size_t)dd*vt_ld + kb + sg*8);
      *(s16x8*)(Klds + key*128 + ((seg*8) ^ ((key&7)<<3))) = kvv;
      *(s16x8*)(Vlds + dd*64  + ((sg*8)  ^ ((dd&7)<<3)))  = vvv;
    }
    __syncthreads();
    f32x4 s[4];
#pragma unroll
    for (int n=0;n<4;n++) s[n] = (f32x4){0,0,0,0};
#pragma unroll
    for (int n=0;n<4;n++){
      int key = n*16 + lr;
#pragma unroll
      for (int kd=0; kd<4; ++kd){
        s16x8 kf = *(const s16x8*)(Klds + key*128 + ((kd*32 + lk*8) ^ ((key&7)<<3)));
        MFMA(s[n], qf[kd], kf);
      }
    }
#pragma unroll
    for (int n=0;n<4;n++){
      bool valid = (kb + n*16 + lr) < Nk;
#pragma unroll
      for (int r=0;r<4;r++){
        float v2 = s[n][r]*scale;
        s[n][r] = valid ? v2 : -1e30f;
      }
    }
    float mx[4];
#pragma unroll
    for (int r=0;r<4;r++) mx[r] = fmaxf(fmaxf(s[0][r],s[1][r]), fmaxf(s[2][r],s[3][r]));
#pragma unroll
    for (int off=1; off<16; off<<=1){
#pragma unroll
      for (int r=0;r<4;r++) mx[r] = fmaxf(mx[r], __shfl_xor(mx[r], off, 64));
    }
    float al[4], rs[4];
#pragma unroll
    for (int r=0;r<4;r++){
      float mnew = fmaxf(mr[r], mx[r]);
      al[r] = __expf(mr[r]-mnew);
      mr[r] = mnew;
      rs[r] = 0.f;
    }
#pragma unroll
    for (int n=0;n<4;n++){
#pragma unroll
      for (int r=0;r<4;r++){
        float p = __expf(s[n][r]-mr[r]);
        rs[r] += p;
        plsm[w][(lk*4+r)*80 + n*16 + lr] = f2b(p);
      }
    }
#pragma unroll
    for (int off=1; off<16; off<<=1){
#pragma unroll
      for (int r=0;r<4;r++) rs[r] += __shfl_xor(rs[r], off, 64);
    }
#pragma unroll
    for (int r=0;r<4;r++) ls[r] = ls[r]*al[r] + rs[r];
#pragma unroll
    for (int cf=0; cf<8; cf++){
#pragma unroll
      for (int r=0;r<4;r++) oacc[cf][r] *= al[r];
    }
    __syncthreads();
#pragma unroll
    for (int kd2=0; kd2<2; ++kd2){
      s16x8 pa = *(const s16x8*)(plsm[w] + lr*80 + kd2*32 + lk*8);
#pragma unroll
      for (int cf=0; cf<8; ++cf){
        int dd = cf*16 + lr;
        s16x8 vb = *(const s16x8*)(Vlds + dd*64 + ((kd2*32 + lk*8) ^ ((dd&7)<<3)));
        MFMA(oacc[cf], pa, vb);
      }
    }
    __syncthreads();
  }
  size_t pbase = ((size_t)u*nchunks + c)*M;
#pragma unroll
  for (int cf=0; cf<8; ++cf){
#pragma unroll
    for (int r=0;r<4;r++){
      int row = r0 + lk*4 + r;
      if (row < M) po[(pbase + row)*128 + cf*16 + lr] = oacc[cf][r];
    }
  }
  if (lr == 0){
#pragma unroll
    for (int r=0;r<4;r++){
      int row = r0 + lk*4 + r;
      if (row < M){ pm[pbase + row] = mr[r]; pl[pbase + row] = ls[r]; }
    }
  }
}

// ---------------- flash combine: merge K-chunks, normalize ------------------
__global__ __launch_bounds__(256) void fcomb_kernel(
    const float* __restrict__ po, const float* __restrict__ pm, const float* __restrict__ pl,
    u16* __restrict__ out_bf, float* __restrict__ out_f,
    int rows, int nunits, int nchunks, long o_hi_stride)
{
  int w = threadIdx.x >> 6, lane = threadIdx.x & 63;
  int gid = blockIdx.x*4 + w;
  if (gid >= nunits*rows) return;
  int u = gid / rows, row = gid - u*rows;
  size_t pb = (size_t)u*nchunks*rows + row;
  float m = -1e30f;
  for (int c=0;c<nchunks;c++) m = fmaxf(m, pm[pb + (size_t)c*rows]);
  float L = 0.f, o0 = 0.f, o1 = 0.f;
  for (int c=0;c<nchunks;c++){
    float wgt = __expf(pm[pb + (size_t)c*rows] - m);
    L += wgt * pl[pb + (size_t)c*rows];
    const float* op = po + (pb + (size_t)c*rows)*128;
    o0 += wgt * op[lane*2];
    o1 += wgt * op[lane*2+1];
  }
  float inv = 1.f/L;
  int uh = u>>2, ul = u&3;
  size_t idx = (size_t)uh*o_hi_stride + (size_t)row*512 + ul*128 + lane*2;
  if (out_bf){ out_bf[idx] = f2b(o0*inv); out_bf[idx+1] = f2b(o1*inv); }
  else       { out_f[idx]  = o0*inv;      out_f[idx+1]  = o1*inv; }
}

// ---------------- LayerNorm: one wave per 512-wide row ----------------------
__global__ __launch_bounds__(256) void ln_kernel(
    const u16* __restrict__ inb, const float* __restrict__ inf,
    const u16* __restrict__ gw, const u16* __restrict__ bw,
    u16* __restrict__ out, int rows)
{
  int w = threadIdx.x >> 6, lane = threadIdx.x & 63;
  int row = blockIdx.x*4 + w;
  if (row >= rows) return;
  float x[8];
  if (inb){
    s16x8 v = ld8(inb + (size_t)row*512 + lane*8);
#pragma unroll
    for (int j=0;j<8;j++) x[j] = b2f((u16)v[j]);
  } else {
    const float* p = inf + (size_t)row*512 + lane*8;
#pragma unroll
    for (int j=0;j<8;j++) x[j] = p[j];
  }
  float s = 0.f;
#pragma unroll
  for (int j=0;j<8;j++) s += x[j];
#pragma unroll
  for (int off=1; off<64; off<<=1) s += __shfl_xor(s, off, 64);
  float mean = s*(1.f/512.f);
  float vs = 0.f;
#pragma unroll
  for (int j=0;j<8;j++){ float d = x[j]-mean; vs += d*d; }
#pragma unroll
  for (int off=1; off<64; off<<=1) vs += __shfl_xor(vs, off, 64);
  float rstd = 1.f/sqrtf(vs*(1.f/512.f) + 1e-5f);
#pragma unroll
  for (int j=0;j<8;j++){
    int c = lane*8+j;
    float y = (x[j]-mean)*rstd*b2f(gw[c]) + b2f(bw[c]);
    out[(size_t)row*512 + c] = f2b(y);
  }
}

// ---------------- quadrant gather: xg[(g,l)] = x[n(g,l)] --------------------
__global__ __launch_bounds__(256) void gather_xg_kernel(const u16* __restrict__ x,
                                                        u16* __restrict__ xg)
{
  int w = threadIdx.x >> 6, lane = threadIdx.x & 63;
  int gl = blockIdx.x*4 + w;
  int g = gl/405, l = gl - g*405;
  int a = g >> 1, b = g & 1, hh = l/27, ww = l - hh*27;
  int n = a*810 + hh*54 + b*27 + ww;
  *(s16x8*)(xg + (size_t)gl*512 + lane*8) = *(const s16x8*)(x + (size_t)n*512 + lane*8);
}

// ---------------- xut = xa0 + mean_g ot[g][row%405] -------------------------
__global__ __launch_bounds__(256) void combine_kernel(const float* __restrict__ xa0,
                                                      const float* __restrict__ ot,
                                                      float* __restrict__ xut)
{
  int w = threadIdx.x >> 6, lane = threadIdx.x & 63;
  int row = blockIdx.x*4 + w;
  int l = row % 405;
  int c = lane*8;
  const float* pa = xa0 + (size_t)row*512 + c;
  float acc[8];
#pragma unroll
  for (int j=0;j<8;j++) acc[j] = pa[j];
#pragma unroll
  for (int g2=0; g2<4; ++g2){
    const float* po = ot + ((size_t)(g2*405+l))*512 + c;
#pragma unroll
    for (int j=0;j<8;j++) acc[j] += 0.25f*po[j];
  }
  float* pw = xut + (size_t)row*512 + c;
#pragma unroll
  for (int j=0;j<8;j++) pw[j] = acc[j];
}

// ---------------- mem_fin[0] = x verbatim (dtype-branched) ------------------
__global__ __launch_bounds__(256) void copy_out_kernel(
    const u16* __restrict__ s16, const float* __restrict__ s32,
    const int* __restrict__ flag, u16* __restrict__ dbf, float* __restrict__ df, int n8)
{
  int i = blockIdx.x*256 + threadIdx.x;
  if (i >= n8) return;
  if (*flag){
    ((f32x4*)df)[i*2]   = ((const f32x4*)s32)[i*2];
    ((f32x4*)df)[i*2+1] = ((const f32x4*)s32)[i*2+1];
  } else {
    ((s16x8*)dbf)[i] = ((const s16x8*)s16)[i];
  }
}

// ---------------------------------------------------------------------------
extern "C" void kernel_launch(void* const* d_in, const int* in_sizes, int n_in,
                              void* d_out, int out_size, void* d_ws, size_t ws_size,
                              hipStream_t stream)
{
  u16* outp16 = (u16*)d_out;
  float* outp32 = (float*)d_out;

  char* wsb = (char*)d_ws;
  size_t off = 0;
  auto alloc = [&](size_t bytes)->void*{
    void* p = wsb + off; off += (bytes + 255) & ~(size_t)255; return p; };

  int* flagp = (int*)alloc(256);

  static const int din_idx[23] = {0, 2,3, 4,5, 6,7, 8,9, 10,11, 12,13,
                                  14,15, 16,17, 18,19, 20,21, 22,23};
  static const int din_n[23]   = {829440, 512,512, 262144,512, 262144,512,
                                  262144,512, 262144,512, 512,512,
                                  1048576,2048, 1048576,512, 512,512,
                                  1048576,2048, 1048576,512};
  NormArgs na;
  u16* cptr[23];
  int total = 0;
  for (int i=0;i<23;i++){ na.src[i] = d_in[din_idx[i]]; na.cumblk[i] = total/512; total += din_n[i]; }
  na.cumblk[23] = total/512;
  u16* canon = (u16*)alloc((size_t)total*2);
  { int c = 0; for (int i=0;i<23;i++){ cptr[i] = canon + c; c += din_n[i]; } }
  const u16 *cx=cptr[0], *cg1=cptr[1], *cb1=cptr[2],
            *cwq=cptr[3], *cbq=cptr[4], *cwk=cptr[5], *cbk=cptr[6],
            *cwv=cptr[7], *cbv=cptr[8], *cwo=cptr[9], *cbo=cptr[10],
            *cg2=cptr[11], *cb2=cptr[12], *cw1s=cptr[13], *cfb1s=cptr[14],
            *cw2s=cptr[15], *cfb2s=cptr[16], *ctg2=cptr[17], *ctb2=cptr[18],
            *cw1t=cptr[19], *cfb1t=cptr[20], *cw2t=cptr[21], *cfb2t=cptr[22];

  u16* wqkvT = (u16*)alloc((size_t)1536*512*2);
  u16* woT  = (u16*)alloc(512*512*2);
  u16* w1sT = (u16*)alloc(2048*512*2);
  u16* w2sT = (u16*)alloc((size_t)512*2048*2);
  u16* w1tT = (u16*)alloc(2048*512*2);
  u16* w2tT = (u16*)alloc((size_t)512*2048*2);
  u16* xn   = (u16*)alloc(1620*512*2);
  u16* qkv  = (u16*)alloc((size_t)1620*1536*2);
  u16* vT   = (u16*)alloc((size_t)512*1664*2);
  u16* attn = (u16*)alloc(1620*512*2);
  float* xu = (float*)alloc((size_t)1620*512*4);
  u16* yb   = (u16*)alloc(1620*512*2);
  u16* hh   = (u16*)alloc((size_t)1620*2048*2);
  float* xa0= (float*)alloc((size_t)1620*512*4);
  u16* xg   = (u16*)alloc(1620*512*2);
  u16* xgT  = (u16*)alloc((size_t)4*512*448*2);
  float* ot = (float*)alloc((size_t)4*405*512*4);
  float* xut= (float*)alloc((size_t)1620*512*4);
  u16* yt   = (u16*)alloc(1620*512*2);
  u16* ht   = (u16*)alloc((size_t)1620*2048*2);
  // flash partials (spatial 4u*8c*1620r*128) — also reused as split-K partials
  float* po = (float*)alloc((size_t)4*8*1620*128*4);
  float* pm = (float*)alloc((size_t)4*8*1620*4);
  float* pl = (float*)alloc((size_t)4*8*1620*4);

  const float scale = 0.08838834764831843f;   // 1/sqrt(128)
  dim3 tb(32,8);

  detect_kernel<<<dim3(1), dim3(64), 0, stream>>>((const u16*)d_in[0], flagp);
  norm_kernel<<<dim3(total/512), dim3(64), 0, stream>>>(na, flagp, canon);

  // batched weight transposes
  {
    TJobs J;
    const u16* srcs[8] = {cwq, cwk, cwv, cwo, cw1s, cw2s, cw1t, cw2t};
    u16* dsts[8] = {wqkvT, wqkvT + (size_t)512*512, wqkvT + (size_t)1024*512,
                    woT, w1sT, w2sT, w1tT, w2tT};
    int Rs[8]   = {512,512,512,512, 512,2048, 512,2048};
    int Cs[8]   = {512,512,512,512, 2048,512, 2048,512};
    int t2 = 0;
    J.cum[0] = 0;
    for (int i=0;i<8;i++){
      J.src[i]=srcs[i]; J.dst[i]=dsts[i]; J.R[i]=Rs[i]; J.C32[i]=Cs[i]/32;
      J.srcld[i]=Cs[i]; J.dstld[i]=Rs[i];
      t2 += (Rs[i]/32)*(Cs[i]/32);
      J.cum[i+1]=t2;
    }
    trans_kernel<<<dim3(t2), tb, 0, stream>>>(J);
  }

  // spatial block (only t=0 of the concat survives)
  ln_kernel<<<dim3(405), dim3(256), 0, stream>>>(cx, nullptr, cg1, cb1, xn, 1620);
  gemm_s_kernel<<<dim3(24,26,1), dim3(256), 0, stream>>>(xn, wqkvT, cbq, cbk, cbv,
      1620,1536,512, 1, nullptr, nullptr,nullptr, qkv, nullptr, nullptr,nullptr,nullptr, 0);
  // vT from qkv V-columns (pad rows 1620..1663 written as 0)
  {
    TJobs J;
    J.src[0]=qkv+1024; J.dst[0]=vT; J.R[0]=1620; J.C32[0]=512/32;
    J.srcld[0]=1536; J.dstld[0]=1664;
    int t2 = (1664/32)*(512/32);
    J.cum[0]=0; for (int i=1;i<9;i++) J.cum[i]=t2;
    trans_kernel<<<dim3(t2), tb, 0, stream>>>(J);
  }
  // spatial flash: 26 q-tiles x 4 heads x 8 key-chunks, 4 waves/block
  flash4_kernel<<<dim3(26,4,8), dim3(256), 0, stream>>>(qkv, qkv+512, vT, po, pm, pl,
      1620, 1620, 1536, 26, 8, 0L, 0L, 1664, scale);
  fcomb_kernel<<<dim3(1620), dim3(256), 0, stream>>>(po, pm, pl, attn, nullptr,
      1620, 4, 8, 0L);
  // O-proj: split-K=2
  gemm_s_kernel<<<dim3(8,26,2), dim3(256), 0, stream>>>(attn, woT, nullptr,nullptr,nullptr,
      1620,512,512, 2, po, nullptr,nullptr, nullptr,nullptr, nullptr,nullptr,nullptr, 0);
  gemm_comb_kernel<<<dim3(405), dim3(256), 0, stream>>>(po, 2, cbo, 1620,512, 0,
      cx, nullptr, nullptr, xu, nullptr,nullptr,nullptr);
  ln_kernel<<<dim3(405), dim3(256), 0, stream>>>(nullptr, xu, cg2, cb2, yb, 1620);
  gemm_s_kernel<<<dim3(32,26,1), dim3(256), 0, stream>>>(yb, w1sT, cfb1s, nullptr,nullptr,
      1620,2048,512, 1, nullptr, nullptr,nullptr, hh, nullptr, nullptr,nullptr,nullptr, 1);
  // FFN2 spatial: split-K=2; epilogue writes xa0 + mem_fin[1]
  gemm_s_kernel<<<dim3(8,26,2), dim3(256), 0, stream>>>(hh, w2sT, nullptr,nullptr,nullptr,
      1620,512,2048, 2, po, nullptr,nullptr, nullptr,nullptr, nullptr,nullptr,nullptr, 0);
  gemm_comb_kernel<<<dim3(405), dim3(256), 0, stream>>>(po, 2, cfb2s, 1620,512, 0,
      nullptr, xu, nullptr, xa0, flagp, outp16 + 1658880, outp32 + 1658880);

  // temporal block (attention input is the ORIGINAL x, grouped by quadrant)
  gather_xg_kernel<<<dim3(405), dim3(256), 0, stream>>>(cx, xg);
  {
    TJobs J;
    int per = (448/32)*(512/32);
    for (int g=0; g<4; ++g){
      J.src[g]=xg + (size_t)g*405*512; J.dst[g]=xgT + (size_t)g*512*448;
      J.R[g]=405; J.C32[g]=512/32; J.srcld[g]=512; J.dstld[g]=448;
    }
    J.cum[0]=0;
    for (int i=1;i<9;i++) J.cum[i] = (i<=4) ? per*i : per*4;
    trans_kernel<<<dim3(per*4), tb, 0, stream>>>(J);
  }
  // temporal flash: 7 q-tiles x 16 (g,h) units x 7 chunks
  flash4_kernel<<<dim3(7,16,7), dim3(256), 0, stream>>>(xg, xg, xgT, po, pm, pl,
      405, 405, 512, 7, 7, (long)(405*512), (long)(512*448), 448, scale);
  fcomb_kernel<<<dim3(1620), dim3(256), 0, stream>>>(po, pm, pl, nullptr, ot,
      405, 16, 7, (long)(405*512));
  combine_kernel<<<dim3(405), dim3(256), 0, stream>>>(xa0, ot, xut);
  ln_kernel<<<dim3(405), dim3(256), 0, stream>>>(nullptr, xut, ctg2, ctb2, yt, 1620);
  gemm_s_kernel<<<dim3(32,26,1), dim3(256), 0, stream>>>(yt, w1tT, cfb1t, nullptr,nullptr,
      1620,2048,512, 1, nullptr, nullptr,nullptr, ht, nullptr, nullptr,nullptr,nullptr, 1);
  gemm_s_kernel<<<dim3(8,26,2), dim3(256), 0, stream>>>(ht, w2tT, nullptr,nullptr,nullptr,
      1620,512,2048, 2, po, nullptr,nullptr, nullptr,nullptr, nullptr,nullptr,nullptr, 0);
  gemm_comb_kernel<<<dim3(405), dim3(256), 0, stream>>>(po, 2, cfb2t, 1620,512, 0,
      nullptr, xut, nullptr, nullptr, flagp, outp16, outp32);

  // mem_fin[0] = x verbatim
  copy_out_kernel<<<dim3(405), dim3(256), 0, stream>>>((const u16*)d_in[0],
      (const float*)d_in[0], flagp, outp16 + 829440, outp32 + 829440, 103680);
}

// Round 10
// 281.753 us; speedup vs baseline: 2.1073x; 1.0941x over previous
//
#include <hip/hip_runtime.h>
#include <stdint.h>

typedef unsigned short u16;
typedef float f32x4 __attribute__((ext_vector_type(4)));
typedef short s16x8 __attribute__((ext_vector_type(8)));

#define DEV __device__ __forceinline__

DEV float b2f(u16 u){ union{unsigned i; float f;} v; v.i = ((unsigned)u)<<16; return v.f; }
DEV u16 f2b(float f){ union{float f; unsigned i;} v; v.f=f; unsigned u=v.i;
                      return (u16)((u + 0x7FFFu + ((u>>16)&1u))>>16); }
DEV s16x8 ld8(const u16* p){ return *(const s16x8*)p; }

#define MFMA(d,a,b) d = __builtin_amdgcn_mfma_f32_16x16x32_bf16(a, b, d, 0, 0, 0)

// async 16B global->LDS (wave-uniform LDS base + lane*16 by construction)
DEV void gload16(const u16* g, u16* l){
  __builtin_amdgcn_global_load_lds((const __attribute__((address_space(1))) void*)g,
                                   (__attribute__((address_space(3))) void*)l, 16, 0, 0);
}

// ---------------- dtype detection: f32 misread as bf16 has wild exponents ---
__global__ __launch_bounds__(64) void detect_kernel(const u16* __restrict__ x, int* flag){
  int lane = threadIdx.x;
  int cnt = 0;
  for (int i=0;i<32;i++){
    u16 v = x[lane*32+i];
    int e = (v >> 7) & 0xFF;
    if (e >= 0xE0) cnt++;           // |val| >= 2^97: impossible for N(0,1) bf16 data
  }
  for (int off=1; off<64; off<<=1) cnt += __shfl_xor(cnt, off, 64);
  if (lane==0) *flag = (cnt >= 16) ? 1 : 0;   // 1 = device buffers are f32
}

// ---------------- canonicalize small tensors to contiguous bf16 -------------
struct NormArgs { const void* src[15]; int cumblk[16]; };

__global__ __launch_bounds__(64) void norm_kernel(NormArgs a, const int* __restrict__ flag,
                                                  u16* __restrict__ canon){
  int b = blockIdx.x, lane = threadIdx.x;
  int t = 0;
  while (t < 14 && b >= a.cumblk[t+1]) t++;
  int off = (b - a.cumblk[t])*512 + lane*8;
  size_t g = (size_t)b*512 + lane*8;
  if (*flag){
    const float* s = (const float*)a.src[t] + off;
    s16x8 o;
#pragma unroll
    for (int j=0;j<8;j++) o[j] = (short)f2b(s[j]);
    *(s16x8*)(canon+g) = o;
  } else {
    *(s16x8*)(canon+g) = *(const s16x8*)((const u16*)a.src[t] + off);
  }
}

// ---------------- batched tiled transpose (dtype-aware source) --------------
struct TJobs {
  const void* src[8]; u16* dst[8];
  int R[8], C32[8], srcld[8], dstld[8];
  int cum[9];
};
__global__ void trans_kernel(TJobs J, const int* __restrict__ flag){
  int b = blockIdx.x;
  int t = 0;
  while (b >= J.cum[t+1]) t++;
  int idx = b - J.cum[t];
  int tr = idx / J.C32[t], tc = idx - tr*J.C32[t];
  int r0 = tr*32, c0 = tc*32;
  const void* src = J.src[t];
  u16* dst = J.dst[t];
  int R = J.R[t], srcld = J.srcld[t], dstld = J.dstld[t];
  int isf32 = flag ? *flag : 0;
  __shared__ u16 tile[32][33];
  int tx = threadIdx.x, ty = threadIdx.y;   // (32,8)
#pragma unroll
  for (int i=0;i<4;i++){
    int r = r0 + ty + i*8, c = c0 + tx;
    u16 v = 0;
    if (r < R){
      size_t si = (size_t)r*srcld + c;
      v = isf32 ? f2b(((const float*)src)[si]) : ((const u16*)src)[si];
    }
    tile[ty+i*8][tx] = v;
  }
  __syncthreads();
#pragma unroll
  for (int i=0;i<4;i++){
    int c = c0 + ty + i*8, r = r0 + tx;
    if (r < dstld) dst[(size_t)c*dstld + r] = tile[tx][ty+i*8];
  }
}

// ---------------- LDS-staged MFMA GEMM: C = A(MxK) @ BT(NxK)^T --------------
// 64x64 tile, BK=64, 4 waves, double-buffered via global_load_lds w=16.
// XOR swizzle on SOURCE addr + same XOR on ds_read (linear LDS dest).
__global__ __launch_bounds__(256) void gemm_s_kernel(
    const u16* __restrict__ A, const u16* __restrict__ BT,
    const u16* __restrict__ bias, const u16* __restrict__ bias2, const u16* __restrict__ bias3,
    int M, int N, int K, int KS, float* __restrict__ pout,
    const u16* __restrict__ resid_bf, const float* __restrict__ resid_f,
    u16* __restrict__ out_bf, float* __restrict__ out_f,
    const int* __restrict__ flagp, u16* __restrict__ dev_bf, float* __restrict__ dev_f,
    int relu)
{
  __shared__ u16 Al[2][64*64];
  __shared__ u16 Bl[2][64*64];
  int tid = threadIdx.x, lane = tid & 63, w = tid >> 6;
  int lr = lane & 15, lk = lane >> 4;
  int wr = w >> 1, wc = w & 1;
  int rowBase = blockIdx.y*64, colBase = blockIdx.x*64;
  int z = blockIdx.z;
  int kStep = K / KS;
  int kOff = kStep * z;
  int nk = kStep >> 6;

  f32x4 acc[2][2] = {{{0,0,0,0},{0,0,0,0}},{{0,0,0,0},{0,0,0,0}}};

  auto STAGE = [&](int buf, int kt){
    int kb = kOff + kt*64;
#pragma unroll
    for (int it=0; it<2; ++it){
      int ch  = it*256 + tid;
      int row = ch >> 3, seg = ch & 7;
      int sseg = (seg ^ (row & 7)) << 3;
      int ar = min(rowBase + row, M-1);
      gload16(A  + (size_t)ar*K + kb + sseg, Al[buf] + ch*8);
      int bc = colBase + row;
      gload16(BT + (size_t)bc*K + kb + sseg, Bl[buf] + ch*8);
    }
  };

  STAGE(0, 0);
  asm volatile("s_waitcnt vmcnt(0)" ::: "memory");
  __syncthreads();
  int cur = 0;
  for (int kt=0; kt<nk; ++kt){
    if (kt+1 < nk) STAGE(cur^1, kt+1);
#pragma unroll
    for (int ks=0; ks<2; ++ks){
      s16x8 af[2], bf[2];
#pragma unroll
      for (int m=0;m<2;m++){
        int ar = wr*32 + m*16 + lr;
        af[m] = *(const s16x8*)(Al[cur] + ar*64 + ((((ks<<2)+lk) ^ (ar&7))<<3));
        int bc = wc*32 + m*16 + lr;
        bf[m] = *(const s16x8*)(Bl[cur] + bc*64 + ((((ks<<2)+lk) ^ (bc&7))<<3));
      }
#pragma unroll
      for (int m=0;m<2;m++)
#pragma unroll
        for (int n=0;n<2;n++) MFMA(acc[m][n], af[m], bf[n]);
    }
    asm volatile("s_waitcnt vmcnt(0)" ::: "memory");
    __syncthreads();
    cur ^= 1;
  }

  if (pout){
    float* pz = pout + (size_t)z*M*N;
#pragma unroll
    for (int m=0;m<2;m++)
#pragma unroll
      for (int n=0;n<2;n++){
        int col = colBase + wc*32 + n*16 + lr;
#pragma unroll
        for (int r=0;r<4;r++){
          int row = rowBase + wr*32 + m*16 + lk*4 + r;
          if (row < M) pz[(size_t)row*N + col] = acc[m][n][r];
        }
      }
    return;
  }
  int isf32 = flagp ? *flagp : 0;
#pragma unroll
  for (int m=0;m<2;m++){
#pragma unroll
    for (int n=0;n<2;n++){
      int col = colBase + wc*32 + n*16 + lr;
      float bv = 0.f;
      if (bias){
        if (bias2){
          const u16* bp = (col < 512) ? bias : ((col < 1024) ? bias2 : bias3);
          bv = b2f(bp[col & 511]);
        } else bv = b2f(bias[col]);
      }
#pragma unroll
      for (int r=0;r<4;r++){
        int row = rowBase + wr*32 + m*16 + lk*4 + r;
        if (row < M){
          float v = acc[m][n][r] + bv;
          if (relu) v = fmaxf(v, 0.f);
          size_t idx = (size_t)row*N + col;
          if (resid_bf) v += b2f(resid_bf[idx]);
          if (resid_f)  v += resid_f[idx];
          if (out_f)  out_f[idx]  = v;
          if (out_bf) out_bf[idx] = f2b(v);
          if (flagp){ if (isf32) dev_f[idx] = v; else dev_bf[idx] = f2b(v); }
        }
      }
    }
  }
}

// ---------------- split-K combine + epilogue (N=512) ------------------------
__global__ __launch_bounds__(256) void gemm_comb_kernel(
    const float* __restrict__ pout, int KS, const u16* __restrict__ bias,
    int M, int relu,
    const u16* __restrict__ resid_bf, const float* __restrict__ resid_f,
    u16* __restrict__ out_bf, float* __restrict__ out_f,
    const int* __restrict__ flagp, u16* __restrict__ dev_bf, float* __restrict__ dev_f)
{
  int w = threadIdx.x >> 6, lane = threadIdx.x & 63;
  int row = blockIdx.x*4 + w;
  if (row >= M) return;
  int c0 = lane*8;
  float acc[8];
  const float* p0 = pout + (size_t)row*512 + c0;
#pragma unroll
  for (int j=0;j<8;j++) acc[j] = p0[j];
  for (int z=1; z<KS; ++z){
    const float* pz = pout + ((size_t)z*M + row)*512 + c0;
#pragma unroll
    for (int j=0;j<8;j++) acc[j] += pz[j];
  }
  int isf32 = flagp ? *flagp : 0;
#pragma unroll
  for (int j=0;j<8;j++){
    int col = c0 + j;
    float v = acc[j] + (bias ? b2f(bias[col]) : 0.f);
    if (relu) v = fmaxf(v, 0.f);
    size_t idx = (size_t)row*512 + col;
    if (resid_bf) v += b2f(resid_bf[idx]);
    if (resid_f)  v += resid_f[idx];
    if (out_f)  out_f[idx]  = v;
    if (out_bf) out_bf[idx] = f2b(v);
    if (flagp){ if (isf32) dev_f[idx] = v; else dev_bf[idx] = f2b(v); }
  }
}

// ---------------- split-K combine + residual + LayerNorm (fused) ------------
__global__ __launch_bounds__(256) void comb_ln_kernel(
    const float* __restrict__ pout, int KS, const u16* __restrict__ bias, int M,
    const u16* __restrict__ resid_bf,
    float* __restrict__ out_f,          // xu (f32)
    const u16* __restrict__ gw, const u16* __restrict__ bw,
    u16* __restrict__ out_ln)           // LN(xu) bf16
{
  int w = threadIdx.x >> 6, lane = threadIdx.x & 63;
  int row = blockIdx.x*4 + w;
  if (row >= M) return;
  int c0 = lane*8;
  float acc[8];
  const float* p0 = pout + (size_t)row*512 + c0;
#pragma unroll
  for (int j=0;j<8;j++) acc[j] = p0[j];
  for (int z=1; z<KS; ++z){
    const float* pz = pout + ((size_t)z*M + row)*512 + c0;
#pragma unroll
    for (int j=0;j<8;j++) acc[j] += pz[j];
  }
  float s = 0.f;
#pragma unroll
  for (int j=0;j<8;j++){
    acc[j] += b2f(bias[c0+j]) + b2f(resid_bf[(size_t)row*512 + c0 + j]);
    out_f[(size_t)row*512 + c0 + j] = acc[j];
    s += acc[j];
  }
#pragma unroll
  for (int off=1; off<64; off<<=1) s += __shfl_xor(s, off, 64);
  float mean = s*(1.f/512.f);
  float vs = 0.f;
#pragma unroll
  for (int j=0;j<8;j++){ float d = acc[j]-mean; vs += d*d; }
#pragma unroll
  for (int off=1; off<64; off<<=1) vs += __shfl_xor(vs, off, 64);
  float rstd = 1.f/sqrtf(vs*(1.f/512.f) + 1e-5f);
#pragma unroll
  for (int j=0;j<8;j++){
    int c = c0+j;
    out_ln[(size_t)row*512 + c] = f2b((acc[j]-mean)*rstd*b2f(gw[c]) + b2f(bw[c]));
  }
}

// ---------------- temporal combine + LayerNorm (fused) ----------------------
// xut = xa0 + mean_g ot[g][row%405]; yt = LN(xut)
__global__ __launch_bounds__(256) void combine_ln_kernel(
    const float* __restrict__ xa0, const float* __restrict__ ot,
    float* __restrict__ xut,
    const u16* __restrict__ gw, const u16* __restrict__ bw,
    u16* __restrict__ out_ln)
{
  int w = threadIdx.x >> 6, lane = threadIdx.x & 63;
  int row = blockIdx.x*4 + w;
  int l = row % 405;
  int c0 = lane*8;
  const float* pa = xa0 + (size_t)row*512 + c0;
  float acc[8];
#pragma unroll
  for (int j=0;j<8;j++) acc[j] = pa[j];
#pragma unroll
  for (int g2=0; g2<4; ++g2){
    const float* po = ot + ((size_t)(g2*405+l))*512 + c0;
#pragma unroll
    for (int j=0;j<8;j++) acc[j] += 0.25f*po[j];
  }
  float s = 0.f;
#pragma unroll
  for (int j=0;j<8;j++){ xut[(size_t)row*512 + c0 + j] = acc[j]; s += acc[j]; }
#pragma unroll
  for (int off=1; off<64; off<<=1) s += __shfl_xor(s, off, 64);
  float mean = s*(1.f/512.f);
  float vs = 0.f;
#pragma unroll
  for (int j=0;j<8;j++){ float d = acc[j]-mean; vs += d*d; }
#pragma unroll
  for (int off=1; off<64; off<<=1) vs += __shfl_xor(vs, off, 64);
  float rstd = 1.f/sqrtf(vs*(1.f/512.f) + 1e-5f);
#pragma unroll
  for (int j=0;j<8;j++){
    int c = c0+j;
    out_ln[(size_t)row*512 + c] = f2b((acc[j]-mean)*rstd*b2f(gw[c]) + b2f(bw[c]));
  }
}

// ---------------- flash partial, 4 waves/block, LDS-staged K/V tiles --------
__global__ __launch_bounds__(256) void flash4_kernel(
    const u16* __restrict__ Qp, const u16* __restrict__ Kp, const u16* __restrict__ VTp,
    float* __restrict__ po, float* __restrict__ pm, float* __restrict__ pl,
    int M, int Nk, int qld, int tiles_total, int nchunks,
    long q_hi_stride, long vt_hi_stride, int vt_ld, float scale)
{
  int u = blockIdx.y, c = blockIdx.z;
  int uh = u >> 2, ul = u & 3;
  const u16* q  = Qp  + (size_t)uh*q_hi_stride + ul*128;
  const u16* kk = Kp  + (size_t)uh*q_hi_stride + ul*128;
  const u16* vt = VTp + (size_t)uh*vt_hi_stride + (size_t)(ul*128)*vt_ld;
  int tid = threadIdx.x, lane = tid & 63, w = tid >> 6;
  int lr = lane & 15, lk = lane >> 4;
  int r0 = blockIdx.x*64 + w*16;
  int qr = min(r0 + lr, M-1);

  __shared__ u16 Klds[64*128];
  __shared__ u16 Vlds[128*64];
  __shared__ u16 plsm[4][16*80];

  s16x8 qf[4];
#pragma unroll
  for (int kd=0; kd<4; ++kd) qf[kd] = ld8(q + (size_t)qr*qld + kd*32 + lk*8);
  f32x4 oacc[8];
#pragma unroll
  for (int i=0;i<8;i++) oacc[i] = (f32x4){0,0,0,0};
  float mr[4] = {-1e30f,-1e30f,-1e30f,-1e30f};
  float ls[4] = {0,0,0,0};

  int t0 = (tiles_total * c) / nchunks;
  int t1 = (tiles_total * (c+1)) / nchunks;
  for (int kt=t0; kt<t1; ++kt){
    int kb = kt*64;
#pragma unroll
    for (int it=0; it<4; ++it){
      int ch = it*256 + tid;
      int key = ch >> 4, seg = ch & 15;
      int kg = min(kb + key, Nk-1);
      s16x8 kvv = ld8(kk + (size_t)kg*qld + seg*8);
      int dd = ch >> 3, sg = ch & 7;
      s16x8 vvv = ld8(vt + (size_t)dd*vt_ld + kb + sg*8);
      *(s16x8*)(Klds + key*128 + ((seg*8) ^ ((key&7)<<3))) = kvv;
      *(s16x8*)(Vlds + dd*64  + ((sg*8)  ^ ((dd&7)<<3)))  = vvv;
    }
    __syncthreads();
    f32x4 s[4];
#pragma unroll
    for (int n=0;n<4;n++) s[n] = (f32x4){0,0,0,0};
    __builtin_amdgcn_s_setprio(1);
#pragma unroll
    for (int n=0;n<4;n++){
      int key = n*16 + lr;
#pragma unroll
      for (int kd=0; kd<4; ++kd){
        s16x8 kf = *(const s16x8*)(Klds + key*128 + ((kd*32 + lk*8) ^ ((key&7)<<3)));
        MFMA(s[n], qf[kd], kf);
      }
    }
    __builtin_amdgcn_s_setprio(0);
#pragma unroll
    for (int n=0;n<4;n++){
      bool valid = (kb + n*16 + lr) < Nk;
#pragma unroll
      for (int r=0;r<4;r++){
        float v2 = s[n][r]*scale;
        s[n][r] = valid ? v2 : -1e30f;
      }
    }
    float mx[4];
#pragma unroll
    for (int r=0;r<4;r++) mx[r] = fmaxf(fmaxf(s[0][r],s[1][r]), fmaxf(s[2][r],s[3][r]));
#pragma unroll
    for (int off=1; off<16; off<<=1){
#pragma unroll
      for (int r=0;r<4;r++) mx[r] = fmaxf(mx[r], __shfl_xor(mx[r], off, 64));
    }
    float al[4], rs[4];
#pragma unroll
    for (int r=0;r<4;r++){
      float mnew = fmaxf(mr[r], mx[r]);
      al[r] = __expf(mr[r]-mnew);
      mr[r] = mnew;
      rs[r] = 0.f;
    }
#pragma unroll
    for (int n=0;n<4;n++){
#pragma unroll
      for (int r=0;r<4;r++){
        float p = __expf(s[n][r]-mr[r]);
        rs[r] += p;
        plsm[w][(lk*4+r)*80 + n*16 + lr] = f2b(p);
      }
    }
#pragma unroll
    for (int off=1; off<16; off<<=1){
#pragma unroll
      for (int r=0;r<4;r++) rs[r] += __shfl_xor(rs[r], off, 64);
    }
#pragma unroll
    for (int r=0;r<4;r++) ls[r] = ls[r]*al[r] + rs[r];
#pragma unroll
    for (int cf=0; cf<8; cf++){
#pragma unroll
      for (int r=0;r<4;r++) oacc[cf][r] *= al[r];
    }
    __syncthreads();
    __builtin_amdgcn_s_setprio(1);
#pragma unroll
    for (int kd2=0; kd2<2; ++kd2){
      s16x8 pa = *(const s16x8*)(plsm[w] + lr*80 + kd2*32 + lk*8);
#pragma unroll
      for (int cf=0; cf<8; ++cf){
        int dd = cf*16 + lr;
        s16x8 vb = *(const s16x8*)(Vlds + dd*64 + ((kd2*32 + lk*8) ^ ((dd&7)<<3)));
        MFMA(oacc[cf], pa, vb);
      }
    }
    __builtin_amdgcn_s_setprio(0);
    __syncthreads();
  }
  size_t pbase = ((size_t)u*nchunks + c)*M;
#pragma unroll
  for (int cf=0; cf<8; ++cf){
#pragma unroll
    for (int r=0;r<4;r++){
      int row = r0 + lk*4 + r;
      if (row < M) po[(pbase + row)*128 + cf*16 + lr] = oacc[cf][r];
    }
  }
  if (lr == 0){
#pragma unroll
    for (int r=0;r<4;r++){
      int row = r0 + lk*4 + r;
      if (row < M){ pm[pbase + row] = mr[r]; pl[pbase + row] = ls[r]; }
    }
  }
}

// ---------------- flash combine: merge K-chunks, normalize ------------------
__global__ __launch_bounds__(256) void fcomb_kernel(
    const float* __restrict__ po, const float* __restrict__ pm, const float* __restrict__ pl,
    u16* __restrict__ out_bf, float* __restrict__ out_f,
    int rows, int nunits, int nchunks, long o_hi_stride)
{
  int w = threadIdx.x >> 6, lane = threadIdx.x & 63;
  int gid = blockIdx.x*4 + w;
  if (gid >= nunits*rows) return;
  int u = gid / rows, row = gid - u*rows;
  size_t pb = (size_t)u*nchunks*rows + row;
  float m = -1e30f;
  for (int c=0;c<nchunks;c++) m = fmaxf(m, pm[pb + (size_t)c*rows]);
  float L = 0.f, o0 = 0.f, o1 = 0.f;
  for (int c=0;c<nchunks;c++){
    float wgt = __expf(pm[pb + (size_t)c*rows] - m);
    L += wgt * pl[pb + (size_t)c*rows];
    const float* op = po + (pb + (size_t)c*rows)*128;
    o0 += wgt * op[lane*2];
    o1 += wgt * op[lane*2+1];
  }
  float inv = 1.f/L;
  int uh = u>>2, ul = u&3;
  size_t idx = (size_t)uh*o_hi_stride + (size_t)row*512 + ul*128 + lane*2;
  if (out_bf){ out_bf[idx] = f2b(o0*inv); out_bf[idx+1] = f2b(o1*inv); }
  else       { out_f[idx]  = o0*inv;      out_f[idx+1]  = o1*inv; }
}

// ---------------- LayerNorm: one wave per 512-wide row ----------------------
__global__ __launch_bounds__(256) void ln_kernel(
    const u16* __restrict__ inb, const float* __restrict__ inf,
    const u16* __restrict__ gw, const u16* __restrict__ bw,
    u16* __restrict__ out, int rows)
{
  int w = threadIdx.x >> 6, lane = threadIdx.x & 63;
  int row = blockIdx.x*4 + w;
  if (row >= rows) return;
  float x[8];
  if (inb){
    s16x8 v = ld8(inb + (size_t)row*512 + lane*8);
#pragma unroll
    for (int j=0;j<8;j++) x[j] = b2f((u16)v[j]);
  } else {
    const float* p = inf + (size_t)row*512 + lane*8;
#pragma unroll
    for (int j=0;j<8;j++) x[j] = p[j];
  }
  float s = 0.f;
#pragma unroll
  for (int j=0;j<8;j++) s += x[j];
#pragma unroll
  for (int off=1; off<64; off<<=1) s += __shfl_xor(s, off, 64);
  float mean = s*(1.f/512.f);
  float vs = 0.f;
#pragma unroll
  for (int j=0;j<8;j++){ float d = x[j]-mean; vs += d*d; }
#pragma unroll
  for (int off=1; off<64; off<<=1) vs += __shfl_xor(vs, off, 64);
  float rstd = 1.f/sqrtf(vs*(1.f/512.f) + 1e-5f);
#pragma unroll
  for (int j=0;j<8;j++){
    int c = lane*8+j;
    float y = (x[j]-mean)*rstd*b2f(gw[c]) + b2f(bw[c]);
    out[(size_t)row*512 + c] = f2b(y);
  }
}

// ---------------- quadrant gather: xg[(g,l)] = x[n(g,l)] --------------------
__global__ __launch_bounds__(256) void gather_xg_kernel(const u16* __restrict__ x,
                                                        u16* __restrict__ xg)
{
  int w = threadIdx.x >> 6, lane = threadIdx.x & 63;
  int gl = blockIdx.x*4 + w;
  int g = gl/405, l = gl - g*405;
  int a = g >> 1, b = g & 1, hh = l/27, ww = l - hh*27;
  int n = a*810 + hh*54 + b*27 + ww;
  *(s16x8*)(xg + (size_t)gl*512 + lane*8) = *(const s16x8*)(x + (size_t)n*512 + lane*8);
}

// ---------------- mem_fin[0] = x verbatim (dtype-branched) ------------------
__global__ __launch_bounds__(256) void copy_out_kernel(
    const u16* __restrict__ s16, const float* __restrict__ s32,
    const int* __restrict__ flag, u16* __restrict__ dbf, float* __restrict__ df, int n8)
{
  int i = blockIdx.x*256 + threadIdx.x;
  if (i >= n8) return;
  if (*flag){
    ((f32x4*)df)[i*2]   = ((const f32x4*)s32)[i*2];
    ((f32x4*)df)[i*2+1] = ((const f32x4*)s32)[i*2+1];
  } else {
    ((s16x8*)dbf)[i] = ((const s16x8*)s16)[i];
  }
}

// ---------------------------------------------------------------------------
extern "C" void kernel_launch(void* const* d_in, const int* in_sizes, int n_in,
                              void* d_out, int out_size, void* d_ws, size_t ws_size,
                              hipStream_t stream)
{
  u16* outp16 = (u16*)d_out;
  float* outp32 = (float*)d_out;

  char* wsb = (char*)d_ws;
  size_t off = 0;
  auto alloc = [&](size_t bytes)->void*{
    void* p = wsb + off; off += (bytes + 255) & ~(size_t)255; return p; };

  int* flagp = (int*)alloc(256);

  // small tensors canonicalized: x, g1,b1, bq,bk,bv,bo, g2,b2, fb1s,fb2s, tg2,tb2, fb1t,fb2t
  static const int din_idx[15] = {0, 2,3, 5,7,9,11, 12,13, 15,17, 18,19, 21,23};
  static const int din_n[15]   = {829440, 512,512, 512,512,512,512, 512,512,
                                  2048,512, 512,512, 2048,512};
  NormArgs na;
  u16* cptr[15];
  int total = 0;
  for (int i=0;i<15;i++){ na.src[i] = d_in[din_idx[i]]; na.cumblk[i] = total/512; total += din_n[i]; }
  na.cumblk[15] = total/512;
  u16* canon = (u16*)alloc((size_t)total*2);
  { int c = 0; for (int i=0;i<15;i++){ cptr[i] = canon + c; c += din_n[i]; } }
  const u16 *cx=cptr[0], *cg1=cptr[1], *cb1=cptr[2],
            *cbq=cptr[3], *cbk=cptr[4], *cbv=cptr[5], *cbo=cptr[6],
            *cg2=cptr[7], *cb2=cptr[8], *cfb1s=cptr[9], *cfb2s=cptr[10],
            *ctg2=cptr[11], *ctb2=cptr[12], *cfb1t=cptr[13], *cfb2t=cptr[14];

  u16* wqkvT = (u16*)alloc((size_t)1536*512*2);
  u16* woT  = (u16*)alloc(512*512*2);
  u16* w1sT = (u16*)alloc(2048*512*2);
  u16* w2sT = (u16*)alloc((size_t)512*2048*2);
  u16* w1tT = (u16*)alloc(2048*512*2);
  u16* w2tT = (u16*)alloc((size_t)512*2048*2);
  u16* xn   = (u16*)alloc(1620*512*2);
  u16* qkv  = (u16*)alloc((size_t)1620*1536*2);
  u16* vT   = (u16*)alloc((size_t)512*1664*2);
  u16* attn = (u16*)alloc(1620*512*2);
  float* xu = (float*)alloc((size_t)1620*512*4);
  u16* yb   = (u16*)alloc(1620*512*2);
  u16* hh   = (u16*)alloc((size_t)1620*2048*2);
  float* xa0= (float*)alloc((size_t)1620*512*4);
  u16* xg   = (u16*)alloc(1620*512*2);
  u16* xgT  = (u16*)alloc((size_t)4*512*448*2);
  float* ot = (float*)alloc((size_t)4*405*512*4);
  float* xut= (float*)alloc((size_t)1620*512*4);
  u16* yt   = (u16*)alloc(1620*512*2);
  u16* ht   = (u16*)alloc((size_t)1620*2048*2);
  float* po = (float*)alloc((size_t)4*4*1620*128*4);
  float* pm = (float*)alloc((size_t)4*4*1620*4);
  float* pl = (float*)alloc((size_t)4*4*1620*4);

  const float scale = 0.08838834764831843f;   // 1/sqrt(128)
  dim3 tb(32,8);

  detect_kernel<<<dim3(1), dim3(64), 0, stream>>>((const u16*)d_in[0], flagp);
  norm_kernel<<<dim3(total/512), dim3(64), 0, stream>>>(na, flagp, canon);

  // batched weight transposes straight from d_in (dtype-aware)
  {
    TJobs J;
    const void* srcs[8] = {d_in[4], d_in[6], d_in[8], d_in[10],
                           d_in[14], d_in[16], d_in[20], d_in[22]};
    u16* dsts[8] = {wqkvT, wqkvT + (size_t)512*512, wqkvT + (size_t)1024*512,
                    woT, w1sT, w2sT, w1tT, w2tT};
    int Rs[8]   = {512,512,512,512, 512,2048, 512,2048};
    int Cs[8]   = {512,512,512,512, 2048,512, 2048,512};
    int t2 = 0;
    J.cum[0] = 0;
    for (int i=0;i<8;i++){
      J.src[i]=srcs[i]; J.dst[i]=dsts[i]; J.R[i]=Rs[i]; J.C32[i]=Cs[i]/32;
      J.srcld[i]=Cs[i]; J.dstld[i]=Rs[i];
      t2 += (Rs[i]/32)*(Cs[i]/32);
      J.cum[i+1]=t2;
    }
    trans_kernel<<<dim3(t2), tb, 0, stream>>>(J, flagp);
  }

  // spatial block (only t=0 of the concat survives)
  ln_kernel<<<dim3(405), dim3(256), 0, stream>>>(cx, nullptr, cg1, cb1, xn, 1620);
  gemm_s_kernel<<<dim3(24,26,1), dim3(256), 0, stream>>>(xn, wqkvT, cbq, cbk, cbv,
      1620,1536,512, 1, nullptr, nullptr,nullptr, qkv, nullptr, nullptr,nullptr,nullptr, 0);
  {
    TJobs J;
    J.src[0]=qkv+1024; J.dst[0]=vT; J.R[0]=1620; J.C32[0]=512/32;
    J.srcld[0]=1536; J.dstld[0]=1664;
    int t2 = (1664/32)*(512/32);
    J.cum[0]=0; for (int i=1;i<9;i++) J.cum[i]=t2;
    trans_kernel<<<dim3(t2), tb, 0, stream>>>(J, nullptr);
  }
  // spatial flash: 26 q-tiles x 4 heads x 4 key-chunks
  flash4_kernel<<<dim3(26,4,4), dim3(256), 0, stream>>>(qkv, qkv+512, vT, po, pm, pl,
      1620, 1620, 1536, 26, 4, 0L, 0L, 1664, scale);
  fcomb_kernel<<<dim3(1620), dim3(256), 0, stream>>>(po, pm, pl, attn, nullptr,
      1620, 4, 4, 0L);
  // O-proj split-K=2, then fused combine+residual+LN
  gemm_s_kernel<<<dim3(8,26,2), dim3(256), 0, stream>>>(attn, woT, nullptr,nullptr,nullptr,
      1620,512,512, 2, po, nullptr,nullptr, nullptr,nullptr, nullptr,nullptr,nullptr, 0);
  comb_ln_kernel<<<dim3(405), dim3(256), 0, stream>>>(po, 2, cbo, 1620, cx, xu,
      cg2, cb2, yb);
  gemm_s_kernel<<<dim3(32,26,1), dim3(256), 0, stream>>>(yb, w1sT, cfb1s, nullptr,nullptr,
      1620,2048,512, 1, nullptr, nullptr,nullptr, hh, nullptr, nullptr,nullptr,nullptr, 1);
  gemm_s_kernel<<<dim3(8,26,2), dim3(256), 0, stream>>>(hh, w2sT, nullptr,nullptr,nullptr,
      1620,512,2048, 2, po, nullptr,nullptr, nullptr,nullptr, nullptr,nullptr,nullptr, 0);
  gemm_comb_kernel<<<dim3(405), dim3(256), 0, stream>>>(po, 2, cfb2s, 1620, 0,
      nullptr, xu, nullptr, xa0, flagp, outp16 + 1658880, outp32 + 1658880);

  // temporal block (attention input is the ORIGINAL x, grouped by quadrant)
  gather_xg_kernel<<<dim3(405), dim3(256), 0, stream>>>(cx, xg);
  {
    TJobs J;
    int per = (448/32)*(512/32);
    for (int g=0; g<4; ++g){
      J.src[g]=xg + (size_t)g*405*512; J.dst[g]=xgT + (size_t)g*512*448;
      J.R[g]=405; J.C32[g]=512/32; J.srcld[g]=512; J.dstld[g]=448;
    }
    J.cum[0]=0;
    for (int i=1;i<9;i++) J.cum[i] = (i<=4) ? per*i : per*4;
    trans_kernel<<<dim3(per*4), tb, 0, stream>>>(J, nullptr);
  }
  // temporal flash: 7 q-tiles x 16 (g,h) units x 4 chunks
  flash4_kernel<<<dim3(7,16,4), dim3(256), 0, stream>>>(xg, xg, xgT, po, pm, pl,
      405, 405, 512, 7, 4, (long)(405*512), (long)(512*448), 448, scale);
  fcomb_kernel<<<dim3(1620), dim3(256), 0, stream>>>(po, pm, pl, nullptr, ot,
      405, 16, 4, (long)(405*512));
  combine_ln_kernel<<<dim3(405), dim3(256), 0, stream>>>(xa0, ot, xut, ctg2, ctb2, yt);
  gemm_s_kernel<<<dim3(32,26,1), dim3(256), 0, stream>>>(yt, w1tT, cfb1t, nullptr,nullptr,
      1620,2048,512, 1, nullptr, nullptr,nullptr, ht, nullptr, nullptr,nullptr,nullptr, 1);
  gemm_s_kernel<<<dim3(8,26,2), dim3(256), 0, stream>>>(ht, w2tT, nullptr,nullptr,nullptr,
      1620,512,2048, 2, po, nullptr,nullptr, nullptr,nullptr, nullptr,nullptr,nullptr, 0);
  gemm_comb_kernel<<<dim3(405), dim3(256), 0, stream>>>(po, 2, cfb2t, 1620, 0,
      nullptr, xut, nullptr, nullptr, flagp, outp16, outp32);

  // mem_fin[0] = x verbatim
  copy_out_kernel<<<dim3(405), dim3(256), 0, stream>>>((const u16*)d_in[0],
      (const float*)d_in[0], flagp, outp16 + 829440, outp32 + 829440, 103680);
}